// Round 4
// baseline (634.316 us; speedup 1.0000x reference)
//
#include <hip/hip_runtime.h>

// ---------------------------------------------------------------------------
// Fused TransformerBlock: x += MSA(LN(x)) twice, then x += MLP(LN(x)).
// B=4 T=1024 C=1024 H=16 hd=64. All activations fp32 at residual level,
// bf16 at GEMM inputs (MFMA 16x16x32_bf16), softmax/LN/reductions fp32.
// ---------------------------------------------------------------------------

#define DEVI __device__ __forceinline__

typedef unsigned short u16;
typedef short bf16x8 __attribute__((ext_vector_type(8)));   // 8 bf16 = 4 VGPR
typedef float f32x4 __attribute__((ext_vector_type(4)));
typedef unsigned short u16x4 __attribute__((ext_vector_type(4)));

DEVI u16 f2bf(float f) {                 // RNE fp32 -> bf16
  union { float f; unsigned u; } v; v.f = f;
  unsigned r = v.u + 0x7FFFu + ((v.u >> 16) & 1u);
  return (u16)(r >> 16);
}

DEVI void gload16(const void* g, void* l) {   // async global->LDS, 16B/lane
  __builtin_amdgcn_global_load_lds((const __attribute__((address_space(1))) void*)g,
                                   (__attribute__((address_space(3))) void*)l,
                                   16, 0, 0);
}

// ---------------------------------------------------------------------------
// Weight packs (fp32 -> bf16, transposed to Bt[N][K] layout for the GEMM)
// ---------------------------------------------------------------------------

// W [16][1024][64] fp32  ->  out rows [h*64+d][1024] bf16
__global__ __launch_bounds__(256) void k_pack_headw(const float* __restrict__ W,
                                                    u16* __restrict__ out) {
  const int k0 = blockIdx.x * 64;
  const int h  = blockIdx.y;
  __shared__ float t[64][65];
  const int tid = threadIdx.x;
#pragma unroll
  for (int p = 0; p < 16; p++) {
    int e = p * 256 + tid, kk = e >> 6, d = e & 63;
    t[kk][d] = W[h * 65536 + (k0 + kk) * 64 + d];
  }
  __syncthreads();
#pragma unroll
  for (int p = 0; p < 16; p++) {
    int e = p * 256 + tid, d = e >> 6, kk = e & 63;
    out[(size_t)(h * 64 + d) * 1024 + k0 + kk] = f2bf(t[kk][d]);
  }
}

// in [R][C] fp32 -> out [C][R] bf16
__global__ __launch_bounds__(256) void k_transpose(const float* __restrict__ in,
                                                   u16* __restrict__ out,
                                                   int R, int C) {
  const int c0 = blockIdx.x * 64, r0 = blockIdx.y * 64;
  __shared__ float t[64][65];
  const int tid = threadIdx.x;
#pragma unroll
  for (int p = 0; p < 16; p++) {
    int e = p * 256 + tid, rr = e >> 6, cc = e & 63;
    t[rr][cc] = in[(size_t)(r0 + rr) * C + c0 + cc];
  }
  __syncthreads();
#pragma unroll
  for (int p = 0; p < 16; p++) {
    int e = p * 256 + tid, cc = e >> 6, rr = e & 63;
    out[(size_t)(c0 + cc) * R + r0 + rr] = f2bf(t[rr][cc]);
  }
}

// ---------------------------------------------------------------------------
// LayerNorm (optionally fused residual add): xv = xin (+ oin); writes fp32
// running residual (xsum) and bf16 normalized output (xn). One block per row.
// ---------------------------------------------------------------------------
__global__ __launch_bounds__(256) void k_ln(const float* __restrict__ xin,
                                            const float* __restrict__ oin,
                                            float* __restrict__ xsum,
                                            u16* __restrict__ xn,
                                            const float* __restrict__ g,
                                            const float* __restrict__ b) {
  const int row = blockIdx.x;
  const size_t base = (size_t)row * 1024;
  const int tid = threadIdx.x;
  float4 xv = ((const float4*)(xin + base))[tid];
  if (oin) {
    float4 ov = ((const float4*)(oin + base))[tid];
    xv.x += ov.x; xv.y += ov.y; xv.z += ov.z; xv.w += ov.w;
  }
  if (xsum) ((float4*)(xsum + base))[tid] = xv;
  float s = xv.x + xv.y + xv.z + xv.w;
  float q = xv.x * xv.x + xv.y * xv.y + xv.z * xv.z + xv.w * xv.w;
#pragma unroll
  for (int m = 1; m < 64; m <<= 1) { s += __shfl_xor(s, m); q += __shfl_xor(q, m); }
  __shared__ float red[8];
  const int wave = tid >> 6, lane = tid & 63;
  if (lane == 0) { red[wave] = s; red[4 + wave] = q; }
  __syncthreads();
  s = red[0] + red[1] + red[2] + red[3];
  q = red[4] + red[5] + red[6] + red[7];
  const float mean = s * (1.f / 1024.f);
  const float var  = q * (1.f / 1024.f) - mean * mean;
  const float rstd = rsqrtf(var + 1e-5f);
  float4 gv = ((const float4*)g)[tid];
  float4 bv = ((const float4*)b)[tid];
  u16x4 o;
  o[0] = f2bf((xv.x - mean) * rstd * gv.x + bv.x);
  o[1] = f2bf((xv.y - mean) * rstd * gv.y + bv.y);
  o[2] = f2bf((xv.z - mean) * rstd * gv.z + bv.z);
  o[3] = f2bf((xv.w - mean) * rstd * gv.w + bv.w);
  *(u16x4*)(xn + base + tid * 4) = o;
}

// ---------------------------------------------------------------------------
// GEMM C[M,N] = A[M,K] * Bt[N,K]^T, bf16 in, fp32 accum. m97 structure:
// 128x128 tile, BK=32, 4 waves (2x2) x 64x64, global_load_lds width-16.
// EPI 0: bf16 store. 1: +bias, relu, bf16. 2: +bias +resid, fp32 store.
// ---------------------------------------------------------------------------
template <int EPI>
__global__ __launch_bounds__(256) void gemm_bt(const u16* __restrict__ A,
                                               const u16* __restrict__ Bt,
                                               void* __restrict__ outp,
                                               const float* __restrict__ bias,
                                               const float* __restrict__ resid,
                                               int M, int N, int K) {
  __shared__ u16 As[128 * 32];
  __shared__ u16 Bs[128 * 32];
  const int tid = threadIdx.x;
  const int wave = tid >> 6, lane = tid & 63;
  const int lg = lane >> 4, l15 = lane & 15;
  const int wr = wave >> 1, wc = wave & 1;
  const int by = blockIdx.y, bx = blockIdx.x;

  const u16* Ab = A + (size_t)by * 128 * K;
  const u16* Bb = Bt + (size_t)bx * 128 * K;

  // staging: 512 chunks of 16B per 8KB tile; thread covers chunk tid and 256+tid
  const int r0 = tid >> 2, c0 = (tid & 3) * 8;
  const int r1 = (256 + tid) >> 2;
  char* lA0 = (char*)As + (wave * 64) * 16;          // wave-uniform LDS dst
  char* lA1 = (char*)As + (256 + wave * 64) * 16;
  char* lB0 = (char*)Bs + (wave * 64) * 16;
  char* lB1 = (char*)Bs + (256 + wave * 64) * 16;

  const f32x4 zero = {0.f, 0.f, 0.f, 0.f};
  f32x4 acc[4][4];
#pragma unroll
  for (int i = 0; i < 4; i++)
#pragma unroll
    for (int j = 0; j < 4; j++) acc[i][j] = zero;

  for (int kk = 0; kk < K; kk += 32) {
    gload16(Ab + (size_t)r0 * K + kk + c0, lA0);
    gload16(Ab + (size_t)r1 * K + kk + c0, lA1);
    gload16(Bb + (size_t)r0 * K + kk + c0, lB0);
    gload16(Bb + (size_t)r1 * K + kk + c0, lB1);
    __syncthreads();   // vmcnt(0) drain + barrier: tiles resident
    bf16x8 af[4], bfv[4];
#pragma unroll
    for (int i = 0; i < 4; i++)
      af[i] = *(const bf16x8*)&As[(wr * 64 + i * 16 + l15) * 32 + lg * 8];
#pragma unroll
    for (int j = 0; j < 4; j++)
      bfv[j] = *(const bf16x8*)&Bs[(wc * 64 + j * 16 + l15) * 32 + lg * 8];
#pragma unroll
    for (int i = 0; i < 4; i++)
#pragma unroll
      for (int j = 0; j < 4; j++)
        acc[i][j] = __builtin_amdgcn_mfma_f32_16x16x32_bf16(af[i], bfv[j], acc[i][j], 0, 0, 0);
    __syncthreads();   // all waves done reading before next stage overwrites
  }

  // C/D layout: col = lane&15, row = (lane>>4)*4 + reg  [m89/m91 verified]
  const int rbase = by * 128 + wr * 64 + lg * 4;
  const int cbase = bx * 128 + wc * 64 + l15;
  if constexpr (EPI == 0) {
    u16* out = (u16*)outp;
#pragma unroll
    for (int i = 0; i < 4; i++)
#pragma unroll
      for (int j = 0; j < 4; j++)
#pragma unroll
        for (int r = 0; r < 4; r++)
          out[(size_t)(rbase + i * 16 + r) * N + cbase + j * 16] = f2bf(acc[i][j][r]);
  } else if constexpr (EPI == 1) {
    u16* out = (u16*)outp;
#pragma unroll
    for (int j = 0; j < 4; j++) {
      const float bv = bias[cbase + j * 16];
#pragma unroll
      for (int i = 0; i < 4; i++)
#pragma unroll
        for (int r = 0; r < 4; r++)
          out[(size_t)(rbase + i * 16 + r) * N + cbase + j * 16] =
              f2bf(fmaxf(acc[i][j][r] + bv, 0.f));
    }
  } else {
    float* out = (float*)outp;
#pragma unroll
    for (int j = 0; j < 4; j++) {
      const float bv = bias[cbase + j * 16];
#pragma unroll
      for (int i = 0; i < 4; i++)
#pragma unroll
        for (int r = 0; r < 4; r++) {
          const size_t idx = (size_t)(rbase + i * 16 + r) * N + cbase + j * 16;
          out[idx] = acc[i][j][r] + bv + resid[idx];
        }
    }
  }
}

// ---------------------------------------------------------------------------
// V transpose: QKV[.,2048+h*64+d] -> Vt[b][h][d][t]  (bf16)
// ---------------------------------------------------------------------------
__global__ __launch_bounds__(256) void k_vt(const u16* __restrict__ QKV,
                                            u16* __restrict__ Vt) {
  const int bh = blockIdx.y, b = bh >> 4, h = bh & 15;
  const int t0 = blockIdx.x * 64;
  __shared__ u16 tile[64][66];
  const int tid = threadIdx.x;
#pragma unroll
  for (int p = 0; p < 16; p++) {
    int e = p * 256 + tid, tt = e >> 6, d = e & 63;
    tile[tt][d] = QKV[(size_t)(b * 1024 + t0 + tt) * 3072 + 2048 + h * 64 + d];
  }
  __syncthreads();
#pragma unroll
  for (int p = 0; p < 16; p++) {
    int e = p * 256 + tid, d = e >> 6, tt = e & 63;
    Vt[((size_t)bh * 64 + d) * 1024 + t0 + tt] = tile[tt][d];
  }
}

// ---------------------------------------------------------------------------
// Flash attention fwd, swapped-QK^T, register double-buffered K/V (T14).
// Block = (b,h) x 64 q-rows, 4 waves x 16 q-rows each. KVBLK=64, two tiles
// per loop body with named reg buffers (static indexing only).
// Loads for tile i+1 issue before compute of tile i -> HBM/L2 latency hides
// under ~1500cy of MFMA+softmax. No LDS. Math identical to round-1 version.
// ---------------------------------------------------------------------------

DEVI void load_kt(bf16x8 (&kr)[8], const u16* base) {   // base: +kv*3072 +kvperm*3072 +lg*8
  kr[0] = *(const bf16x8*)(base);
  kr[1] = *(const bf16x8*)(base + 32);
  kr[2] = *(const bf16x8*)(base + 4 * 3072);
  kr[3] = *(const bf16x8*)(base + 4 * 3072 + 32);
  kr[4] = *(const bf16x8*)(base + 32 * 3072);
  kr[5] = *(const bf16x8*)(base + 32 * 3072 + 32);
  kr[6] = *(const bf16x8*)(base + 36 * 3072);
  kr[7] = *(const bf16x8*)(base + 36 * 3072 + 32);
}

DEVI void load_vt8(bf16x8 (&vr)[8], const u16* vbase) {  // vbase: +l15*1024 +kv +lg*8
#pragma unroll
  for (int dg = 0; dg < 4; dg++) {
    vr[2 * dg]     = *(const bf16x8*)(vbase + (size_t)dg * 16 * 1024);
    vr[2 * dg + 1] = *(const bf16x8*)(vbase + (size_t)dg * 16 * 1024 + 32);
  }
}

DEVI void attn_tile(const bf16x8 (&kr)[8], const bf16x8 (&vr)[8],
                    bf16x8 qf0, bf16x8 qf1, f32x4 (&oa)[4],
                    float& m, float& sden, int lg, float cexp) {
  const f32x4 zero = {0.f, 0.f, 0.f, 0.f};
  f32x4 s0 = zero, s1 = zero, s2 = zero, s3 = zero;
  s0 = __builtin_amdgcn_mfma_f32_16x16x32_bf16(kr[0], qf0, s0, 0, 0, 0);
  s0 = __builtin_amdgcn_mfma_f32_16x16x32_bf16(kr[1], qf1, s0, 0, 0, 0);
  s1 = __builtin_amdgcn_mfma_f32_16x16x32_bf16(kr[2], qf0, s1, 0, 0, 0);
  s1 = __builtin_amdgcn_mfma_f32_16x16x32_bf16(kr[3], qf1, s1, 0, 0, 0);
  s2 = __builtin_amdgcn_mfma_f32_16x16x32_bf16(kr[4], qf0, s2, 0, 0, 0);
  s2 = __builtin_amdgcn_mfma_f32_16x16x32_bf16(kr[5], qf1, s2, 0, 0, 0);
  s3 = __builtin_amdgcn_mfma_f32_16x16x32_bf16(kr[6], qf0, s3, 0, 0, 0);
  s3 = __builtin_amdgcn_mfma_f32_16x16x32_bf16(kr[7], qf1, s3, 0, 0, 0);
  // lane holds S[kv = 8*lg + {0..3,4..7,32..35,36..39}][q = l15]

  f32x4 mv = s0;
#pragma unroll
  for (int r = 0; r < 4; r++) mv[r] = fmaxf(fmaxf(mv[r], s1[r]), fmaxf(s2[r], s3[r]));
  float mx = fmaxf(fmaxf(mv[0], mv[1]), fmaxf(mv[2], mv[3]));
  mx = fmaxf(mx, __shfl_xor(mx, 16));
  mx = fmaxf(mx, __shfl_xor(mx, 32));
  const float mn = fmaxf(m, mx);
  const float fr = exp2f((m - mn) * cexp);
  m = mn;
#pragma unroll
  for (int r = 0; r < 4; r++) {
    s0[r] = exp2f((s0[r] - mn) * cexp);
    s1[r] = exp2f((s1[r] - mn) * cexp);
    s2[r] = exp2f((s2[r] - mn) * cexp);
    s3[r] = exp2f((s3[r] - mn) * cexp);
  }
  f32x4 sv = (s0 + s1) + (s2 + s3);
  float ts = (sv[0] + sv[1]) + (sv[2] + sv[3]);
  ts += __shfl_xor(ts, 16);
  ts += __shfl_xor(ts, 32);
  sden = sden * fr + ts;

  bf16x8 pa0, pa1;
#pragma unroll
  for (int r = 0; r < 4; r++) {
    pa0[r]     = (short)f2bf(s0[r]);
    pa0[4 + r] = (short)f2bf(s1[r]);
    pa1[r]     = (short)f2bf(s2[r]);
    pa1[4 + r] = (short)f2bf(s3[r]);
  }

  float frq[4];
#pragma unroll
  for (int r = 0; r < 4; r++) frq[r] = __shfl(fr, 20 * lg + r, 64);
#pragma unroll
  for (int dg = 0; dg < 4; dg++) {
    oa[dg][0] *= frq[0]; oa[dg][1] *= frq[1];
    oa[dg][2] *= frq[2]; oa[dg][3] *= frq[3];
    oa[dg] = __builtin_amdgcn_mfma_f32_16x16x32_bf16(pa0, vr[2 * dg],     oa[dg], 0, 0, 0);
    oa[dg] = __builtin_amdgcn_mfma_f32_16x16x32_bf16(pa1, vr[2 * dg + 1], oa[dg], 0, 0, 0);
  }
}

__global__ __launch_bounds__(256) void k_attn(const u16* __restrict__ QKV,
                                              const u16* __restrict__ Vt,
                                              float* __restrict__ O) {
  const int Tn = 1024;
  const int bh = blockIdx.x, b = bh >> 4, h = bh & 15;
  const int q0 = blockIdx.y * 64;
  const int tid = threadIdx.x, wave = tid >> 6, lane = tid & 63;
  const int lg = lane >> 4, l15 = lane & 15;

  const u16* Qb = QKV + (size_t)(b * Tn + q0 + wave * 16 + l15) * 3072 + h * 64 + lg * 8;
  const bf16x8 qf0 = *(const bf16x8*)Qb;
  const bf16x8 qf1 = *(const bf16x8*)(Qb + 32);

  const int kvperm = 8 * (l15 >> 2) + (l15 & 3);   // A-row -> kv within tile
  const u16* Kbp = QKV + (size_t)(b * Tn) * 3072 + 1024 + h * 64 + lg * 8
                   + (size_t)kvperm * 3072;
  const u16* Vbp = Vt + (size_t)bh * 64 * Tn + (size_t)l15 * Tn + lg * 8;

  const float cexp = 0.03125f * 1.44269504f;       // C^-0.5 * log2(e)

  float m = -1e30f, sden = 0.f;
  const f32x4 zero = {0.f, 0.f, 0.f, 0.f};
  f32x4 oa[4] = {zero, zero, zero, zero};

  bf16x8 ka[8], va[8], kb[8], vb[8];
  load_kt(ka, Kbp);
  load_vt8(va, Vbp);

  for (int kv = 0; kv < Tn; kv += 128) {
    // prefetch tile kv+64 (always in-range: kv+64 <= 960)
    load_kt(kb, Kbp + (size_t)(kv + 64) * 3072);
    load_vt8(vb, Vbp + kv + 64);
    attn_tile(ka, va, qf0, qf1, oa, m, sden, lg, cexp);
    if (kv + 128 < Tn) {           // prefetch tile kv+128
      load_kt(ka, Kbp + (size_t)(kv + 128) * 3072);
      load_vt8(va, Vbp + kv + 128);
    }
    attn_tile(kb, vb, qf0, qf1, oa, m, sden, lg, cexp);
  }

  float sdq[4];
#pragma unroll
  for (int r = 0; r < 4; r++) sdq[r] = 1.f / __shfl(sden, 20 * lg + r, 64);
  float* Ob = O + (size_t)(b * Tn + q0 + wave * 16) * 1024 + h * 64;
#pragma unroll
  for (int dg = 0; dg < 4; dg++)
#pragma unroll
    for (int r = 0; r < 4; r++)
      Ob[(size_t)(lg * 4 + r) * 1024 + dg * 16 + l15] = oa[dg][r] * sdq[r];
}

// ---------------------------------------------------------------------------
// Launch
// ---------------------------------------------------------------------------
extern "C" void kernel_launch(void* const* d_in, const int* in_sizes, int n_in,
                              void* d_out, int out_size, void* d_ws, size_t ws_size,
                              hipStream_t stream) {
  const float* x   = (const float*)d_in[0];
  const float* Wq1 = (const float*)d_in[1];
  const float* Wk1 = (const float*)d_in[2];
  const float* Wv1 = (const float*)d_in[3];
  const float* Wq2 = (const float*)d_in[4];
  const float* Wk2 = (const float*)d_in[5];
  const float* Wv2 = (const float*)d_in[6];
  const float* g1  = (const float*)d_in[7];
  const float* b1  = (const float*)d_in[8];
  const float* g2  = (const float*)d_in[9];
  const float* b2  = (const float*)d_in[10];
  const float* g3  = (const float*)d_in[11];
  const float* b3  = (const float*)d_in[12];
  const float* W1  = (const float*)d_in[13];
  const float* bf1 = (const float*)d_in[14];
  const float* W2  = (const float*)d_in[15];
  const float* bf2 = (const float*)d_in[16];

  char* ws = (char*)d_ws;
  // layout (bytes):
  u16* Wqkv1t = (u16*)(ws);                    //  6,291,456  [3072][1024]
  u16* Wqkv2t = (u16*)(ws + 6291456);          //  6,291,456
  u16* W1t    = (u16*)(ws + 12582912);         //  8,388,608  [4096][1024]
  u16* W2t    = (u16*)(ws + 20971520);         //  8,388,608  [1024][4096]
  u16* xn     = (u16*)(ws + 29360128);         //  8,388,608  [4096][1024]
  u16* QKV    = (u16*)(ws + 37748736);         // 25,165,824  [4096][3072]
  u16* Vt     = (u16*)(ws + 62914560);         //  8,388,608  [64][64][1024]
  float* O    = (float*)(ws + 71303168);       // 16,777,216  [4096][1024]
  u16* h1     = (u16*)(ws + 37748736);         // 33,554,432  aliases QKV+Vt (dead by MLP)
  float* xacc = (float*)d_out;                 // fp32 running residual lives in d_out
  // total ws = 88,080,384 bytes

  const dim3 blk(256);

  // weight packs
  k_pack_headw<<<dim3(16, 16), blk, 0, stream>>>(Wq1, Wqkv1t);
  k_pack_headw<<<dim3(16, 16), blk, 0, stream>>>(Wk1, Wqkv1t + 1024 * 1024);
  k_pack_headw<<<dim3(16, 16), blk, 0, stream>>>(Wv1, Wqkv1t + 2048 * 1024);
  k_pack_headw<<<dim3(16, 16), blk, 0, stream>>>(Wq2, Wqkv2t);
  k_pack_headw<<<dim3(16, 16), blk, 0, stream>>>(Wk2, Wqkv2t + 1024 * 1024);
  k_pack_headw<<<dim3(16, 16), blk, 0, stream>>>(Wv2, Wqkv2t + 2048 * 1024);
  k_transpose<<<dim3(64, 16), blk, 0, stream>>>(W1, W1t, 1024, 4096);
  k_transpose<<<dim3(16, 64), blk, 0, stream>>>(W2, W2t, 4096, 1024);

  // ---- layer 1 MSA ----
  k_ln<<<4096, blk, 0, stream>>>(x, nullptr, nullptr, xn, g1, b1);
  gemm_bt<0><<<dim3(24, 32), blk, 0, stream>>>(xn, Wqkv1t, QKV, nullptr, nullptr, 4096, 3072, 1024);
  k_vt<<<dim3(16, 64), blk, 0, stream>>>(QKV, Vt);
  k_attn<<<dim3(64, 16), blk, 0, stream>>>(QKV, Vt, O);
  // x2 = x + O; xn = LN(x2)
  k_ln<<<4096, blk, 0, stream>>>(x, O, xacc, xn, g2, b2);

  // ---- layer 2 MSA ----
  gemm_bt<0><<<dim3(24, 32), blk, 0, stream>>>(xn, Wqkv2t, QKV, nullptr, nullptr, 4096, 3072, 1024);
  k_vt<<<dim3(16, 64), blk, 0, stream>>>(QKV, Vt);
  k_attn<<<dim3(64, 16), blk, 0, stream>>>(QKV, Vt, O);
  // x3 = x2 + O (in place in d_out); xn = LN(x3)
  k_ln<<<4096, blk, 0, stream>>>(xacc, O, xacc, xn, g3, b3);

  // ---- MLP ----
  gemm_bt<1><<<dim3(32, 32), blk, 0, stream>>>(xn, W1t, h1, bf1, nullptr, 4096, 4096, 1024);
  gemm_bt<2><<<dim3(8, 32), blk, 0, stream>>>(h1, W2t, (void*)xacc, bf2, xacc, 4096, 1024, 4096);

  (void)in_sizes; (void)n_in; (void)out_size; (void)ws_size;
}

// Round 5
// 492.136 us; speedup vs baseline: 1.2889x; 1.2889x over previous
//
#include <hip/hip_runtime.h>

// ---------------------------------------------------------------------------
// Fused TransformerBlock: x += MSA(LN(x)) twice, then x += MLP(LN(x)).
// B=4 T=1024 C=1024 H=16 hd=64. fp32 residuals, bf16 GEMM/MFMA inputs.
// Round-5 change: K/V pre-packed into MFMA-fragment order (Kp/Vp) so k_attn
// loads are fully coalesced 1KB streams; 32 q-rows/wave halves K/V re-reads.
// ---------------------------------------------------------------------------

#define DEVI __device__ __forceinline__

typedef unsigned short u16;
typedef short bf16x8 __attribute__((ext_vector_type(8)));   // 8 bf16 = 4 VGPR
typedef float f32x4 __attribute__((ext_vector_type(4)));
typedef unsigned short u16x4 __attribute__((ext_vector_type(4)));

DEVI u16 f2bf(float f) {                 // RNE fp32 -> bf16
  union { float f; unsigned u; } v; v.f = f;
  unsigned r = v.u + 0x7FFFu + ((v.u >> 16) & 1u);
  return (u16)(r >> 16);
}
DEVI float bf2f(u16 u) {
  union { unsigned u; float f; } v; v.u = ((unsigned)u) << 16; return v.f;
}

DEVI void gload16(const void* g, void* l) {   // async global->LDS, 16B/lane
  __builtin_amdgcn_global_load_lds((const __attribute__((address_space(1))) void*)g,
                                   (__attribute__((address_space(3))) void*)l,
                                   16, 0, 0);
}

// ---------------------------------------------------------------------------
// Weight packs (fp32 -> bf16, transposed to Bt[N][K] layout for the GEMM)
// ---------------------------------------------------------------------------

// W [16][1024][64] fp32  ->  out rows [h*64+d][1024] bf16
__global__ __launch_bounds__(256) void k_pack_headw(const float* __restrict__ W,
                                                    u16* __restrict__ out) {
  const int k0 = blockIdx.x * 64;
  const int h  = blockIdx.y;
  __shared__ float t[64][65];
  const int tid = threadIdx.x;
#pragma unroll
  for (int p = 0; p < 16; p++) {
    int e = p * 256 + tid, kk = e >> 6, d = e & 63;
    t[kk][d] = W[h * 65536 + (k0 + kk) * 64 + d];
  }
  __syncthreads();
#pragma unroll
  for (int p = 0; p < 16; p++) {
    int e = p * 256 + tid, d = e >> 6, kk = e & 63;
    out[(size_t)(h * 64 + d) * 1024 + k0 + kk] = f2bf(t[kk][d]);
  }
}

// in [R][C] fp32 -> out [C][R] bf16
__global__ __launch_bounds__(256) void k_transpose(const float* __restrict__ in,
                                                   u16* __restrict__ out,
                                                   int R, int C) {
  const int c0 = blockIdx.x * 64, r0 = blockIdx.y * 64;
  __shared__ float t[64][65];
  const int tid = threadIdx.x;
#pragma unroll
  for (int p = 0; p < 16; p++) {
    int e = p * 256 + tid, rr = e >> 6, cc = e & 63;
    t[rr][cc] = in[(size_t)(r0 + rr) * C + c0 + cc];
  }
  __syncthreads();
#pragma unroll
  for (int p = 0; p < 16; p++) {
    int e = p * 256 + tid, cc = e >> 6, rr = e & 63;
    out[(size_t)(c0 + cc) * R + r0 + rr] = f2bf(t[rr][cc]);
  }
}

// ---------------------------------------------------------------------------
// LayerNorm (+ optional bf16 residual add): xv = xin (+ oin); writes fp32
// running residual (xsum) and bf16 normalized output (xn). One block per row.
// ---------------------------------------------------------------------------
__global__ __launch_bounds__(256) void k_ln(const float* __restrict__ xin,
                                            const u16* __restrict__ oin,
                                            float* __restrict__ xsum,
                                            u16* __restrict__ xn,
                                            const float* __restrict__ g,
                                            const float* __restrict__ b) {
  const int row = blockIdx.x;
  const size_t base = (size_t)row * 1024;
  const int tid = threadIdx.x;
  float4 xv = ((const float4*)(xin + base))[tid];
  if (oin) {
    u16x4 ov = *(const u16x4*)(oin + base + tid * 4);
    xv.x += bf2f(ov[0]); xv.y += bf2f(ov[1]);
    xv.z += bf2f(ov[2]); xv.w += bf2f(ov[3]);
  }
  if (xsum) ((float4*)(xsum + base))[tid] = xv;
  float s = xv.x + xv.y + xv.z + xv.w;
  float q = xv.x * xv.x + xv.y * xv.y + xv.z * xv.z + xv.w * xv.w;
#pragma unroll
  for (int m = 1; m < 64; m <<= 1) { s += __shfl_xor(s, m); q += __shfl_xor(q, m); }
  __shared__ float red[8];
  const int wave = tid >> 6, lane = tid & 63;
  if (lane == 0) { red[wave] = s; red[4 + wave] = q; }
  __syncthreads();
  s = red[0] + red[1] + red[2] + red[3];
  q = red[4] + red[5] + red[6] + red[7];
  const float mean = s * (1.f / 1024.f);
  const float var  = q * (1.f / 1024.f) - mean * mean;
  const float rstd = rsqrtf(var + 1e-5f);
  float4 gv = ((const float4*)g)[tid];
  float4 bv = ((const float4*)b)[tid];
  u16x4 o;
  o[0] = f2bf((xv.x - mean) * rstd * gv.x + bv.x);
  o[1] = f2bf((xv.y - mean) * rstd * gv.y + bv.y);
  o[2] = f2bf((xv.z - mean) * rstd * gv.z + bv.z);
  o[3] = f2bf((xv.w - mean) * rstd * gv.w + bv.w);
  *(u16x4*)(xn + base + tid * 4) = o;
}

// ---------------------------------------------------------------------------
// GEMM C[M,N] = A[M,K] * Bt[N,K]^T, bf16 in, fp32 accum. m97 structure.
// EPI 0: bf16 store. 1: +bias, relu, bf16. 2: +bias +resid, fp32 store.
// ---------------------------------------------------------------------------
template <int EPI>
__global__ __launch_bounds__(256) void gemm_bt(const u16* __restrict__ A,
                                               const u16* __restrict__ Bt,
                                               void* __restrict__ outp,
                                               const float* __restrict__ bias,
                                               const float* __restrict__ resid,
                                               int M, int N, int K) {
  __shared__ u16 As[128 * 32];
  __shared__ u16 Bs[128 * 32];
  const int tid = threadIdx.x;
  const int wave = tid >> 6, lane = tid & 63;
  const int lg = lane >> 4, l15 = lane & 15;
  const int wr = wave >> 1, wc = wave & 1;
  const int by = blockIdx.y, bx = blockIdx.x;

  const u16* Ab = A + (size_t)by * 128 * K;
  const u16* Bb = Bt + (size_t)bx * 128 * K;

  const int r0 = tid >> 2, c0 = (tid & 3) * 8;
  const int r1 = (256 + tid) >> 2;
  char* lA0 = (char*)As + (wave * 64) * 16;
  char* lA1 = (char*)As + (256 + wave * 64) * 16;
  char* lB0 = (char*)Bs + (wave * 64) * 16;
  char* lB1 = (char*)Bs + (256 + wave * 64) * 16;

  const f32x4 zero = {0.f, 0.f, 0.f, 0.f};
  f32x4 acc[4][4];
#pragma unroll
  for (int i = 0; i < 4; i++)
#pragma unroll
    for (int j = 0; j < 4; j++) acc[i][j] = zero;

  for (int kk = 0; kk < K; kk += 32) {
    gload16(Ab + (size_t)r0 * K + kk + c0, lA0);
    gload16(Ab + (size_t)r1 * K + kk + c0, lA1);
    gload16(Bb + (size_t)r0 * K + kk + c0, lB0);
    gload16(Bb + (size_t)r1 * K + kk + c0, lB1);
    __syncthreads();
    bf16x8 af[4], bfv[4];
#pragma unroll
    for (int i = 0; i < 4; i++)
      af[i] = *(const bf16x8*)&As[(wr * 64 + i * 16 + l15) * 32 + lg * 8];
#pragma unroll
    for (int j = 0; j < 4; j++)
      bfv[j] = *(const bf16x8*)&Bs[(wc * 64 + j * 16 + l15) * 32 + lg * 8];
#pragma unroll
    for (int i = 0; i < 4; i++)
#pragma unroll
      for (int j = 0; j < 4; j++)
        acc[i][j] = __builtin_amdgcn_mfma_f32_16x16x32_bf16(af[i], bfv[j], acc[i][j], 0, 0, 0);
    __syncthreads();
  }

  const int rbase = by * 128 + wr * 64 + lg * 4;
  const int cbase = bx * 128 + wc * 64 + l15;
  if constexpr (EPI == 0) {
    u16* out = (u16*)outp;
#pragma unroll
    for (int i = 0; i < 4; i++)
#pragma unroll
      for (int j = 0; j < 4; j++)
#pragma unroll
        for (int r = 0; r < 4; r++)
          out[(size_t)(rbase + i * 16 + r) * N + cbase + j * 16] = f2bf(acc[i][j][r]);
  } else if constexpr (EPI == 1) {
    u16* out = (u16*)outp;
#pragma unroll
    for (int j = 0; j < 4; j++) {
      const float bv = bias[cbase + j * 16];
#pragma unroll
      for (int i = 0; i < 4; i++)
#pragma unroll
        for (int r = 0; r < 4; r++)
          out[(size_t)(rbase + i * 16 + r) * N + cbase + j * 16] =
              f2bf(fmaxf(acc[i][j][r] + bv, 0.f));
    }
  } else {
    float* out = (float*)outp;
#pragma unroll
    for (int j = 0; j < 4; j++) {
      const float bv = bias[cbase + j * 16];
#pragma unroll
      for (int i = 0; i < 4; i++)
#pragma unroll
        for (int r = 0; r < 4; r++) {
          const size_t idx = (size_t)(rbase + i * 16 + r) * N + cbase + j * 16;
          out[idx] = acc[i][j][r] + bv + resid[idx];
        }
    }
  }
}

// ---------------------------------------------------------------------------
// K/V fragment pack. Block = (kv-tile t, bh). Stages the 64x64 bf16 tile in
// LDS (coalesced global reads), emits MFMA-fragment-ordered chunks:
//   Kp[(bh*16+t)*512 + c]*8 : c = i*64+lane, i = {koff,half}:
//       K[t*64 + perm(l15) + koff(i>>1)][ (i&1)*32 + lg*8 ..+7 ]
//   Vp[(bh*16+t)*512 + c]*8 : i = {dg,kh}:
//       V[t*64 + (i&1)*32 + lg*8 + jj][ (i>>1)*16 + l15 ]   (transposed)
// where perm(l) = 8*(l>>2) + (l&3), koff(j) = (j&1)*4 + (j>>1)*32.
// In k_attn all loads become lane-linear: chunk c at base + i*512 + lane*8.
// ---------------------------------------------------------------------------
__global__ __launch_bounds__(256) void k_packkv(const u16* __restrict__ QKV,
                                                u16* __restrict__ Kp,
                                                u16* __restrict__ Vp) {
  const int t  = blockIdx.x;               // kv tile 0..15
  const int bh = blockIdx.y, b = bh >> 4, h = bh & 15;
  const int tid = threadIdx.x;
  __shared__ u16 vt[64][80];               // 80: 16B-aligned rows, bank-spread

  const u16* Ksrc = QKV + (size_t)(b * 1024 + t * 64) * 3072 + 1024 + h * 64;
  const u16* Vsrc = QKV + (size_t)(b * 1024 + t * 64) * 3072 + 2048 + h * 64;
  u16* KpT = Kp + (size_t)(bh * 16 + t) * 4096;
  u16* VpT = Vp + (size_t)(bh * 16 + t) * 4096;

  // ---- stage K tile, emit Kp ----
#pragma unroll
  for (int p = 0; p < 2; p++) {
    int e = p * 256 + tid, rr = e >> 3, dd = (e & 7) * 8;
    *(bf16x8*)&vt[rr][dd] = *(const bf16x8*)(Ksrc + (size_t)rr * 3072 + dd);
  }
  __syncthreads();
#pragma unroll
  for (int p = 0; p < 2; p++) {
    int c = p * 256 + tid;
    int i = c >> 6, lane = c & 63, lgg = lane >> 4, ll = lane & 15;
    int j = i >> 1;
    int row = 8 * (ll >> 2) + (ll & 3) + (j & 1) * 4 + (j >> 1) * 32;
    int col = (i & 1) * 32 + lgg * 8;
    *(bf16x8*)&KpT[(size_t)c * 8] = *(const bf16x8*)&vt[row][col];
  }
  __syncthreads();
  // ---- stage V tile, emit Vp (transposed) ----
#pragma unroll
  for (int p = 0; p < 2; p++) {
    int e = p * 256 + tid, rr = e >> 3, dd = (e & 7) * 8;
    *(bf16x8*)&vt[rr][dd] = *(const bf16x8*)(Vsrc + (size_t)rr * 3072 + dd);
  }
  __syncthreads();
#pragma unroll
  for (int p = 0; p < 2; p++) {
    int c = p * 256 + tid;
    int i = c >> 6, lane = c & 63, lgg = lane >> 4, ll = lane & 15;
    int dg = (i >> 1) & 3, kh = i & 1;
    bf16x8 o;
#pragma unroll
    for (int jj = 0; jj < 8; jj++)
      o[jj] = (short)vt[kh * 32 + lgg * 8 + jj][dg * 16 + ll];
    *(bf16x8*)&VpT[(size_t)c * 8] = o;
  }
}

// ---------------------------------------------------------------------------
// Flash attention fwd. Swapped QK^T, fragment-packed K/V (coalesced streams),
// 32 q-rows per wave (two 16-row halves share K/V regs), KVBLK=64, reg dbuf.
// Block = (b,h) x 128 q-rows, 4 waves. No LDS. O written bf16.
// ---------------------------------------------------------------------------
DEVI void load8(bf16x8 (&r)[8], const u16* p) {   // p includes +lane*8
#pragma unroll
  for (int i = 0; i < 8; i++) r[i] = *(const bf16x8*)(p + i * 512);
}

DEVI void attn_tile32(const bf16x8 (&kr)[8], const bf16x8 (&vr)[8],
                      const bf16x8 (&qf)[2][2], f32x4 (&oa)[2][4],
                      float (&m)[2], float (&sden)[2], int lg, float cexp) {
  const f32x4 zero = {0.f, 0.f, 0.f, 0.f};
#pragma unroll
  for (int qh = 0; qh < 2; qh++) {
    f32x4 s0 = zero, s1 = zero, s2 = zero, s3 = zero;
    s0 = __builtin_amdgcn_mfma_f32_16x16x32_bf16(kr[0], qf[qh][0], s0, 0, 0, 0);
    s0 = __builtin_amdgcn_mfma_f32_16x16x32_bf16(kr[1], qf[qh][1], s0, 0, 0, 0);
    s1 = __builtin_amdgcn_mfma_f32_16x16x32_bf16(kr[2], qf[qh][0], s1, 0, 0, 0);
    s1 = __builtin_amdgcn_mfma_f32_16x16x32_bf16(kr[3], qf[qh][1], s1, 0, 0, 0);
    s2 = __builtin_amdgcn_mfma_f32_16x16x32_bf16(kr[4], qf[qh][0], s2, 0, 0, 0);
    s2 = __builtin_amdgcn_mfma_f32_16x16x32_bf16(kr[5], qf[qh][1], s2, 0, 0, 0);
    s3 = __builtin_amdgcn_mfma_f32_16x16x32_bf16(kr[6], qf[qh][0], s3, 0, 0, 0);
    s3 = __builtin_amdgcn_mfma_f32_16x16x32_bf16(kr[7], qf[qh][1], s3, 0, 0, 0);
    // lane holds S[kv = 8*lg + {0..3,4..7,32..35,36..39}][q = l15]

    f32x4 mv = s0;
#pragma unroll
    for (int r = 0; r < 4; r++) mv[r] = fmaxf(fmaxf(mv[r], s1[r]), fmaxf(s2[r], s3[r]));
    float mx = fmaxf(fmaxf(mv[0], mv[1]), fmaxf(mv[2], mv[3]));
    mx = fmaxf(mx, __shfl_xor(mx, 16));
    mx = fmaxf(mx, __shfl_xor(mx, 32));
    const float mn = fmaxf(m[qh], mx);
    const float fr = exp2f((m[qh] - mn) * cexp);
    m[qh] = mn;
#pragma unroll
    for (int r = 0; r < 4; r++) {
      s0[r] = exp2f((s0[r] - mn) * cexp);
      s1[r] = exp2f((s1[r] - mn) * cexp);
      s2[r] = exp2f((s2[r] - mn) * cexp);
      s3[r] = exp2f((s3[r] - mn) * cexp);
    }
    f32x4 sv = (s0 + s1) + (s2 + s3);
    float ts = (sv[0] + sv[1]) + (sv[2] + sv[3]);
    ts += __shfl_xor(ts, 16);
    ts += __shfl_xor(ts, 32);
    sden[qh] = sden[qh] * fr + ts;

    bf16x8 pa0, pa1;
#pragma unroll
    for (int r = 0; r < 4; r++) {
      pa0[r]     = (short)f2bf(s0[r]);
      pa0[4 + r] = (short)f2bf(s1[r]);
      pa1[r]     = (short)f2bf(s2[r]);
      pa1[4 + r] = (short)f2bf(s3[r]);
    }

    float frq[4];
#pragma unroll
    for (int r = 0; r < 4; r++) frq[r] = __shfl(fr, 20 * lg + r, 64);
#pragma unroll
    for (int dg = 0; dg < 4; dg++) {
      oa[qh][dg][0] *= frq[0]; oa[qh][dg][1] *= frq[1];
      oa[qh][dg][2] *= frq[2]; oa[qh][dg][3] *= frq[3];
      oa[qh][dg] = __builtin_amdgcn_mfma_f32_16x16x32_bf16(pa0, vr[2 * dg],     oa[qh][dg], 0, 0, 0);
      oa[qh][dg] = __builtin_amdgcn_mfma_f32_16x16x32_bf16(pa1, vr[2 * dg + 1], oa[qh][dg], 0, 0, 0);
    }
  }
}

__global__ __launch_bounds__(256) void k_attn(const u16* __restrict__ QKV,
                                              const u16* __restrict__ Kp,
                                              const u16* __restrict__ Vp,
                                              u16* __restrict__ O) {
  const int Tn = 1024;
  const int bh = blockIdx.x, b = bh >> 4, h = bh & 15;
  const int q0 = blockIdx.y * 128;
  const int tid = threadIdx.x, wave = tid >> 6, lane = tid & 63;
  const int lg = lane >> 4, l15 = lane & 15;

  const u16* Qb = QKV + (size_t)(b * Tn + q0 + wave * 32 + l15) * 3072 + h * 64 + lg * 8;
  bf16x8 qf[2][2];
  qf[0][0] = *(const bf16x8*)Qb;
  qf[0][1] = *(const bf16x8*)(Qb + 32);
  qf[1][0] = *(const bf16x8*)(Qb + 16 * 3072);
  qf[1][1] = *(const bf16x8*)(Qb + 16 * 3072 + 32);

  const u16* KpB = Kp + (size_t)bh * 65536 + lane * 8;
  const u16* VpB = Vp + (size_t)bh * 65536 + lane * 8;

  const float cexp = 0.03125f * 1.44269504f;       // C^-0.5 * log2(e)

  float m[2] = {-1e30f, -1e30f}, sden[2] = {0.f, 0.f};
  const f32x4 zero = {0.f, 0.f, 0.f, 0.f};
  f32x4 oa[2][4];
#pragma unroll
  for (int qh = 0; qh < 2; qh++)
#pragma unroll
    for (int dg = 0; dg < 4; dg++) oa[qh][dg] = zero;

  bf16x8 ka[8], va[8], kb[8], vb[8];
  load8(ka, KpB);
  load8(va, VpB);

  for (int t = 0; t < 16; t += 2) {
    load8(kb, KpB + (t + 1) * 4096);
    load8(vb, VpB + (t + 1) * 4096);
    attn_tile32(ka, va, qf, oa, m, sden, lg, cexp);
    if (t + 2 < 16) {
      load8(ka, KpB + (t + 2) * 4096);
      load8(va, VpB + (t + 2) * 4096);
    }
    attn_tile32(kb, vb, qf, oa, m, sden, lg, cexp);
  }

#pragma unroll
  for (int qh = 0; qh < 2; qh++) {
    float sdq[4];
#pragma unroll
    for (int r = 0; r < 4; r++) sdq[r] = 1.f / __shfl(sden[qh], 20 * lg + r, 64);
    u16* Ob = O + (size_t)(b * Tn + q0 + wave * 32 + qh * 16) * 1024 + h * 64;
#pragma unroll
    for (int dg = 0; dg < 4; dg++)
#pragma unroll
      for (int r = 0; r < 4; r++)
        Ob[(size_t)(lg * 4 + r) * 1024 + dg * 16 + l15] = f2bf(oa[qh][dg][r] * sdq[r]);
  }
}

// ---------------------------------------------------------------------------
// Launch
// ---------------------------------------------------------------------------
extern "C" void kernel_launch(void* const* d_in, const int* in_sizes, int n_in,
                              void* d_out, int out_size, void* d_ws, size_t ws_size,
                              hipStream_t stream) {
  const float* x   = (const float*)d_in[0];
  const float* Wq1 = (const float*)d_in[1];
  const float* Wk1 = (const float*)d_in[2];
  const float* Wv1 = (const float*)d_in[3];
  const float* Wq2 = (const float*)d_in[4];
  const float* Wk2 = (const float*)d_in[5];
  const float* Wv2 = (const float*)d_in[6];
  const float* g1  = (const float*)d_in[7];
  const float* b1  = (const float*)d_in[8];
  const float* g2  = (const float*)d_in[9];
  const float* b2  = (const float*)d_in[10];
  const float* g3  = (const float*)d_in[11];
  const float* b3  = (const float*)d_in[12];
  const float* W1  = (const float*)d_in[13];
  const float* bf1 = (const float*)d_in[14];
  const float* W2  = (const float*)d_in[15];
  const float* bf2 = (const float*)d_in[16];

  char* ws = (char*)d_ws;
  // layout (bytes):
  u16* Wqkv1t = (u16*)(ws);                    //  6,291,456  [3072][1024]
  u16* Wqkv2t = (u16*)(ws + 6291456);          //  6,291,456
  u16* W1t    = (u16*)(ws + 12582912);         //  8,388,608  [4096][1024]
  u16* W2t    = (u16*)(ws + 20971520);         //  8,388,608  [1024][4096]
  u16* xn     = (u16*)(ws + 29360128);         //  8,388,608  [4096][1024]
  u16* QKV    = (u16*)(ws + 37748736);         // 25,165,824  [4096][3072]
  u16* Kp     = (u16*)(ws + 62914560);         //  8,388,608  frag-packed K
  u16* Vp     = (u16*)(ws + 71303168);         //  8,388,608  frag-packed V
  u16* O      = (u16*)(ws + 79691776);         //  8,388,608  attn out (bf16)
  u16* h1     = (u16*)(ws + 37748736);         // 33,554,432  aliases QKV+Kp (dead by MLP)
  float* xacc = (float*)d_out;                 // fp32 running residual in d_out
  // total ws = 88,080,384 bytes (same as round 1)

  const dim3 blk(256);

  // weight packs
  k_pack_headw<<<dim3(16, 16), blk, 0, stream>>>(Wq1, Wqkv1t);
  k_pack_headw<<<dim3(16, 16), blk, 0, stream>>>(Wk1, Wqkv1t + 1024 * 1024);
  k_pack_headw<<<dim3(16, 16), blk, 0, stream>>>(Wv1, Wqkv1t + 2048 * 1024);
  k_pack_headw<<<dim3(16, 16), blk, 0, stream>>>(Wq2, Wqkv2t);
  k_pack_headw<<<dim3(16, 16), blk, 0, stream>>>(Wk2, Wqkv2t + 1024 * 1024);
  k_pack_headw<<<dim3(16, 16), blk, 0, stream>>>(Wv2, Wqkv2t + 2048 * 1024);
  k_transpose<<<dim3(64, 16), blk, 0, stream>>>(W1, W1t, 1024, 4096);
  k_transpose<<<dim3(16, 64), blk, 0, stream>>>(W2, W2t, 4096, 1024);

  // ---- layer 1 MSA ----
  k_ln<<<4096, blk, 0, stream>>>(x, nullptr, nullptr, xn, g1, b1);
  gemm_bt<0><<<dim3(24, 32), blk, 0, stream>>>(xn, Wqkv1t, QKV, nullptr, nullptr, 4096, 3072, 1024);
  k_packkv<<<dim3(16, 64), blk, 0, stream>>>(QKV, Kp, Vp);
  k_attn<<<dim3(64, 8), blk, 0, stream>>>(QKV, Kp, Vp, O);
  // x2 = x + O; xn = LN(x2)
  k_ln<<<4096, blk, 0, stream>>>(x, O, xacc, xn, g2, b2);

  // ---- layer 2 MSA ----
  gemm_bt<0><<<dim3(24, 32), blk, 0, stream>>>(xn, Wqkv2t, QKV, nullptr, nullptr, 4096, 3072, 1024);
  k_packkv<<<dim3(16, 64), blk, 0, stream>>>(QKV, Kp, Vp);
  k_attn<<<dim3(64, 8), blk, 0, stream>>>(QKV, Kp, Vp, O);
  // x3 = x2 + O (in place in d_out); xn = LN(x3)
  k_ln<<<4096, blk, 0, stream>>>(xacc, O, xacc, xn, g3, b3);

  // ---- MLP ----
  gemm_bt<1><<<dim3(32, 32), blk, 0, stream>>>(xn, W1t, h1, bf1, nullptr, 4096, 4096, 1024);
  gemm_bt<2><<<dim3(8, 32), blk, 0, stream>>>(h1, W2t, (void*)xacc, bf2, xacc, 4096, 1024, 4096);

  (void)in_sizes; (void)n_in; (void)out_size; (void)ws_size;
}

// Round 7
// 454.601 us; speedup vs baseline: 1.3953x; 1.0826x over previous
//
#include <hip/hip_runtime.h>

// ---------------------------------------------------------------------------
// Fused TransformerBlock: x += MSA(LN(x)) twice, then x += MLP(LN(x)).
// B=4 T=1024 C=1024 H=16 hd=64. fp32 residuals, bf16 GEMM/MFMA inputs.
// Round-6: GEMM overhaul — 2-phase pipelined LDS dbuf (stage t+1 before
// compute t, one barrier/iter), source-side XOR swizzle (bank-conflict-free
// ds_read_b128 with linear global_load_lds dest), MLP2 split-K=2 + combine.
// ---------------------------------------------------------------------------

#define DEVI __device__ __forceinline__

typedef unsigned short u16;
typedef short bf16x8 __attribute__((ext_vector_type(8)));   // 8 bf16 = 4 VGPR
typedef float f32x4 __attribute__((ext_vector_type(4)));
typedef unsigned short u16x4 __attribute__((ext_vector_type(4)));

DEVI u16 f2bf(float f) {                 // RNE fp32 -> bf16
  union { float f; unsigned u; } v; v.f = f;
  unsigned r = v.u + 0x7FFFu + ((v.u >> 16) & 1u);
  return (u16)(r >> 16);
}
DEVI float bf2f(u16 u) {
  union { unsigned u; float f; } v; v.u = ((unsigned)u) << 16; return v.f;
}

DEVI void gload16(const void* g, void* l) {   // async global->LDS, 16B/lane
  __builtin_amdgcn_global_load_lds((const __attribute__((address_space(1))) void*)g,
                                   (__attribute__((address_space(3))) void*)l,
                                   16, 0, 0);
}

// ---------------------------------------------------------------------------
// Weight packs (fp32 -> bf16, transposed to Bt[N][K] layout for the GEMM)
// ---------------------------------------------------------------------------

// W [16][1024][64] fp32  ->  out rows [h*64+d][1024] bf16
__global__ __launch_bounds__(256) void k_pack_headw(const float* __restrict__ W,
                                                    u16* __restrict__ out) {
  const int k0 = blockIdx.x * 64;
  const int h  = blockIdx.y;
  __shared__ float t[64][65];
  const int tid = threadIdx.x;
#pragma unroll
  for (int p = 0; p < 16; p++) {
    int e = p * 256 + tid, kk = e >> 6, d = e & 63;
    t[kk][d] = W[h * 65536 + (k0 + kk) * 64 + d];
  }
  __syncthreads();
#pragma unroll
  for (int p = 0; p < 16; p++) {
    int e = p * 256 + tid, d = e >> 6, kk = e & 63;
    out[(size_t)(h * 64 + d) * 1024 + k0 + kk] = f2bf(t[kk][d]);
  }
}

// in [R][C] fp32 -> out [C][R] bf16
__global__ __launch_bounds__(256) void k_transpose(const float* __restrict__ in,
                                                   u16* __restrict__ out,
                                                   int R, int C) {
  const int c0 = blockIdx.x * 64, r0 = blockIdx.y * 64;
  __shared__ float t[64][65];
  const int tid = threadIdx.x;
#pragma unroll
  for (int p = 0; p < 16; p++) {
    int e = p * 256 + tid, rr = e >> 6, cc = e & 63;
    t[rr][cc] = in[(size_t)(r0 + rr) * C + c0 + cc];
  }
  __syncthreads();
#pragma unroll
  for (int p = 0; p < 16; p++) {
    int e = p * 256 + tid, cc = e >> 6, rr = e & 63;
    out[(size_t)(c0 + cc) * R + r0 + rr] = f2bf(t[rr][cc]);
  }
}

// ---------------------------------------------------------------------------
// LayerNorm (+ optional bf16 residual add): xv = xin (+ oin); writes fp32
// running residual (xsum) and bf16 normalized output (xn). One block per row.
// ---------------------------------------------------------------------------
__global__ __launch_bounds__(256) void k_ln(const float* __restrict__ xin,
                                            const u16* __restrict__ oin,
                                            float* __restrict__ xsum,
                                            u16* __restrict__ xn,
                                            const float* __restrict__ g,
                                            const float* __restrict__ b) {
  const int row = blockIdx.x;
  const size_t base = (size_t)row * 1024;
  const int tid = threadIdx.x;
  float4 xv = ((const float4*)(xin + base))[tid];
  if (oin) {
    u16x4 ov = *(const u16x4*)(oin + base + tid * 4);
    xv.x += bf2f(ov[0]); xv.y += bf2f(ov[1]);
    xv.z += bf2f(ov[2]); xv.w += bf2f(ov[3]);
  }
  if (xsum) ((float4*)(xsum + base))[tid] = xv;
  float s = xv.x + xv.y + xv.z + xv.w;
  float q = xv.x * xv.x + xv.y * xv.y + xv.z * xv.z + xv.w * xv.w;
#pragma unroll
  for (int m = 1; m < 64; m <<= 1) { s += __shfl_xor(s, m); q += __shfl_xor(q, m); }
  __shared__ float red[8];
  const int wave = tid >> 6, lane = tid & 63;
  if (lane == 0) { red[wave] = s; red[4 + wave] = q; }
  __syncthreads();
  s = red[0] + red[1] + red[2] + red[3];
  q = red[4] + red[5] + red[6] + red[7];
  const float mean = s * (1.f / 1024.f);
  const float var  = q * (1.f / 1024.f) - mean * mean;
  const float rstd = rsqrtf(var + 1e-5f);
  float4 gv = ((const float4*)g)[tid];
  float4 bv = ((const float4*)b)[tid];
  u16x4 o;
  o[0] = f2bf((xv.x - mean) * rstd * gv.x + bv.x);
  o[1] = f2bf((xv.y - mean) * rstd * gv.y + bv.y);
  o[2] = f2bf((xv.z - mean) * rstd * gv.z + bv.z);
  o[3] = f2bf((xv.w - mean) * rstd * gv.w + bv.w);
  *(u16x4*)(xn + base + tid * 4) = o;
}

// ---------------------------------------------------------------------------
// GEMM C[M,N] = A[M,K] * Bt[N,K]^T, bf16 in, fp32 accum.
// 128x128 tile, BK=32, 4 waves (2x2) x 64x64. 2-phase pipeline: LDS double
// buffer, STAGE(t+1) issued before COMPUTE(t), one __syncthreads per iter
// (its vmcnt(0)+barrier = the T3 "minimum 2-phase" recipe).
// Swizzle (rule #21 both-sides): linear gload_lds dest; global SOURCE column
// quad pre-XORed with (row>>1)&3; ds_read applies the same XOR. 16 lanes ->
// 8 bank-quads x 2 (2-way = free).
// EPI 0: bf16 store. 1: +bias relu bf16. 3: split-K fp32 partial (z picks
// outp/outp2, K-range [z*K/2,(z+1)*K/2)).
// ---------------------------------------------------------------------------
template <int EPI>
__global__ __launch_bounds__(256, 4) void gemm_bt(const u16* __restrict__ A,
                                                  const u16* __restrict__ Bt,
                                                  void* __restrict__ outp,
                                                  void* __restrict__ outp2,
                                                  const float* __restrict__ bias,
                                                  int M, int N, int K) {
  __shared__ u16 As[2][128 * 32];
  __shared__ u16 Bs[2][128 * 32];
  const int tid = threadIdx.x;
  const int wave = tid >> 6, lane = tid & 63;
  const int lg = lane >> 4, l15 = lane & 15;
  const int wr = wave >> 1, wc = wave & 1;
  const int by = blockIdx.y, bx = blockIdx.x;

  const int Ksz   = (EPI == 3) ? (K >> 1) : K;
  const int kbase = (EPI == 3) ? (int)blockIdx.z * Ksz : 0;

  const u16* Ab = A + (size_t)by * 128 * K;
  const u16* Bb = Bt + (size_t)bx * 128 * K;

  // staging chunks: c1 = tid -> (row r0, quad q); c2 = 256+tid -> (r0+64, q)
  const int r0 = tid >> 2, q = tid & 3, r1 = r0 + 64;
  const int c0s = (q ^ ((r0 >> 1) & 3)) * 8;   // swizzled source col (elems)
  const int c1s = (q ^ ((r1 >> 1) & 3)) * 8;
  // wave-uniform LDS bases (lane*16 added by HW)
  char* const a0[2] = {(char*)As[0] + wave * 1024, (char*)As[1] + wave * 1024};
  char* const a1[2] = {(char*)As[0] + 4096 + wave * 1024, (char*)As[1] + 4096 + wave * 1024};
  char* const b0[2] = {(char*)Bs[0] + wave * 1024, (char*)Bs[1] + wave * 1024};
  char* const b1[2] = {(char*)Bs[0] + 4096 + wave * 1024, (char*)Bs[1] + 4096 + wave * 1024};

#define STAGE(b, kk)                                       \
  gload16(Ab + (size_t)r0 * K + (kk) + c0s, a0[b]);        \
  gload16(Ab + (size_t)r1 * K + (kk) + c1s, a1[b]);        \
  gload16(Bb + (size_t)r0 * K + (kk) + c0s, b0[b]);        \
  gload16(Bb + (size_t)r1 * K + (kk) + c1s, b1[b]);

  // fragment byte offsets (loop-invariant; swizzled)
  int aoff[4], boff[4];
#pragma unroll
  for (int i = 0; i < 4; i++) {
    int Ra = wr * 64 + i * 16 + l15;
    aoff[i] = Ra * 64 + ((lg ^ ((Ra >> 1) & 3)) << 4);
    int Rb = wc * 64 + i * 16 + l15;
    boff[i] = Rb * 64 + ((lg ^ ((Rb >> 1) & 3)) << 4);
  }

  const f32x4 zero = {0.f, 0.f, 0.f, 0.f};
  f32x4 acc[4][4];
#pragma unroll
  for (int i = 0; i < 4; i++)
#pragma unroll
    for (int j = 0; j < 4; j++) acc[i][j] = zero;

#define COMPUTE(b)                                                             \
  {                                                                            \
    bf16x8 af[4], bfv[4];                                                      \
    _Pragma("unroll") for (int i = 0; i < 4; i++)                              \
        af[i] = *(const bf16x8*)((const char*)As[b] + aoff[i]);                \
    _Pragma("unroll") for (int j = 0; j < 4; j++)                              \
        bfv[j] = *(const bf16x8*)((const char*)Bs[b] + boff[j]);               \
    _Pragma("unroll") for (int i = 0; i < 4; i++)                              \
        _Pragma("unroll") for (int j = 0; j < 4; j++)                          \
            acc[i][j] = __builtin_amdgcn_mfma_f32_16x16x32_bf16(               \
                af[i], bfv[j], acc[i][j], 0, 0, 0);                            \
  }

  const int NT = Ksz >> 5;          // 32 (K=1024) or 64 (split K=4096): even
  STAGE(0, kbase);
  __syncthreads();                  // buf0 resident
  for (int t = 0; t < NT; t += 2) {
    STAGE(1, kbase + (t + 1) * 32);   // issue next tile, then compute current
    COMPUTE(0);
    __syncthreads();                  // buf1 resident; all reads of buf0 done
    if (t + 2 < NT) { STAGE(0, kbase + (t + 2) * 32); }
    COMPUTE(1);
    __syncthreads();
  }
#undef STAGE
#undef COMPUTE

  // C/D layout: col = lane&15, row = (lane>>4)*4 + reg  [m89/m91 verified]
  const int rbase = by * 128 + wr * 64 + lg * 4;
  const int cbase = bx * 128 + wc * 64 + l15;
  if constexpr (EPI == 0) {
    u16* out = (u16*)outp;
#pragma unroll
    for (int i = 0; i < 4; i++)
#pragma unroll
      for (int j = 0; j < 4; j++)
#pragma unroll
        for (int r = 0; r < 4; r++)
          out[(size_t)(rbase + i * 16 + r) * N + cbase + j * 16] = f2bf(acc[i][j][r]);
  } else if constexpr (EPI == 1) {
    u16* out = (u16*)outp;
#pragma unroll
    for (int j = 0; j < 4; j++) {
      const float bv = bias[cbase + j * 16];
#pragma unroll
      for (int i = 0; i < 4; i++)
#pragma unroll
        for (int r = 0; r < 4; r++)
          out[(size_t)(rbase + i * 16 + r) * N + cbase + j * 16] =
              f2bf(fmaxf(acc[i][j][r] + bv, 0.f));
    }
  } else {
    float* out = blockIdx.z ? (float*)outp2 : (float*)outp;
#pragma unroll
    for (int i = 0; i < 4; i++)
#pragma unroll
      for (int j = 0; j < 4; j++)
#pragma unroll
        for (int r = 0; r < 4; r++)
          out[(size_t)(rbase + i * 16 + r) * N + cbase + j * 16] = acc[i][j][r];
  }
}

// combine split-K partials: xacc += P0 + P1 + bias  (one row per block)
__global__ __launch_bounds__(256) void k_comb(const float* __restrict__ P0,
                                              const float* __restrict__ P1,
                                              const float* __restrict__ bias,
                                              float* __restrict__ xacc) {
  const size_t i = (size_t)blockIdx.x * 1024 + threadIdx.x * 4;
  float4 a = *(const float4*)(P0 + i);
  float4 b = *(const float4*)(P1 + i);
  float4 x = *(const float4*)(xacc + i);
  float4 bv = *(const float4*)(bias + threadIdx.x * 4);
  x.x += a.x + b.x + bv.x;
  x.y += a.y + b.y + bv.y;
  x.z += a.z + b.z + bv.z;
  x.w += a.w + b.w + bv.w;
  *(float4*)(xacc + i) = x;
}

// ---------------------------------------------------------------------------
// K/V fragment pack. Block = (kv-tile t, bh). Stages the 64x64 bf16 tile in
// LDS (coalesced global reads), emits MFMA-fragment-ordered chunks so k_attn
// loads are lane-linear 1KB streams.
// ---------------------------------------------------------------------------
__global__ __launch_bounds__(256) void k_packkv(const u16* __restrict__ QKV,
                                                u16* __restrict__ Kp,
                                                u16* __restrict__ Vp) {
  const int t  = blockIdx.x;               // kv tile 0..15
  const int bh = blockIdx.y, b = bh >> 4, h = bh & 15;
  const int tid = threadIdx.x;
  __shared__ u16 vt[64][80];               // 80: 16B-aligned rows, bank-spread

  const u16* Ksrc = QKV + (size_t)(b * 1024 + t * 64) * 3072 + 1024 + h * 64;
  const u16* Vsrc = QKV + (size_t)(b * 1024 + t * 64) * 3072 + 2048 + h * 64;
  u16* KpT = Kp + (size_t)(bh * 16 + t) * 4096;
  u16* VpT = Vp + (size_t)(bh * 16 + t) * 4096;

  // ---- stage K tile, emit Kp ----
#pragma unroll
  for (int p = 0; p < 2; p++) {
    int e = p * 256 + tid, rr = e >> 3, dd = (e & 7) * 8;
    *(bf16x8*)&vt[rr][dd] = *(const bf16x8*)(Ksrc + (size_t)rr * 3072 + dd);
  }
  __syncthreads();
#pragma unroll
  for (int p = 0; p < 2; p++) {
    int c = p * 256 + tid;
    int i = c >> 6, lane = c & 63, lgg = lane >> 4, ll = lane & 15;
    int j = i >> 1;
    int row = 8 * (ll >> 2) + (ll & 3) + (j & 1) * 4 + (j >> 1) * 32;
    int col = (i & 1) * 32 + lgg * 8;
    *(bf16x8*)&KpT[(size_t)c * 8] = *(const bf16x8*)&vt[row][col];
  }
  __syncthreads();
  // ---- stage V tile, emit Vp (transposed) ----
#pragma unroll
  for (int p = 0; p < 2; p++) {
    int e = p * 256 + tid, rr = e >> 3, dd = (e & 7) * 8;
    *(bf16x8*)&vt[rr][dd] = *(const bf16x8*)(Vsrc + (size_t)rr * 3072 + dd);
  }
  __syncthreads();
#pragma unroll
  for (int p = 0; p < 2; p++) {
    int c = p * 256 + tid;
    int i = c >> 6, lane = c & 63, lgg = lane >> 4, ll = lane & 15;
    int dg = (i >> 1) & 3, kh = i & 1;
    bf16x8 o;
#pragma unroll
    for (int jj = 0; jj < 8; jj++)
      o[jj] = (short)vt[kh * 32 + lgg * 8 + jj][dg * 16 + ll];
    *(bf16x8*)&VpT[(size_t)c * 8] = o;
  }
}

// ---------------------------------------------------------------------------
// Flash attention fwd. Swapped QK^T, fragment-packed K/V (coalesced streams),
// 32 q-rows per wave (two 16-row halves share K/V regs), KVBLK=64, reg dbuf.
// Block = (b,h) x 128 q-rows, 4 waves. No LDS. O written bf16.
// ---------------------------------------------------------------------------
DEVI void load8(bf16x8 (&r)[8], const u16* p) {   // p includes +lane*8
#pragma unroll
  for (int i = 0; i < 8; i++) r[i] = *(const bf16x8*)(p + i * 512);
}

DEVI void attn_tile32(const bf16x8 (&kr)[8], const bf16x8 (&vr)[8],
                      const bf16x8 (&qf)[2][2], f32x4 (&oa)[2][4],
                      float (&m)[2], float (&sden)[2], int lg, float cexp) {
  const f32x4 zero = {0.f, 0.f, 0.f, 0.f};
#pragma unroll
  for (int qh = 0; qh < 2; qh++) {
    f32x4 s0 = zero, s1 = zero, s2 = zero, s3 = zero;
    s0 = __builtin_amdgcn_mfma_f32_16x16x32_bf16(kr[0], qf[qh][0], s0, 0, 0, 0);
    s0 = __builtin_amdgcn_mfma_f32_16x16x32_bf16(kr[1], qf[qh][1], s0, 0, 0, 0);
    s1 = __builtin_amdgcn_mfma_f32_16x16x32_bf16(kr[2], qf[qh][0], s1, 0, 0, 0);
    s1 = __builtin_amdgcn_mfma_f32_16x16x32_bf16(kr[3], qf[qh][1], s1, 0, 0, 0);
    s2 = __builtin_amdgcn_mfma_f32_16x16x32_bf16(kr[4], qf[qh][0], s2, 0, 0, 0);
    s2 = __builtin_amdgcn_mfma_f32_16x16x32_bf16(kr[5], qf[qh][1], s2, 0, 0, 0);
    s3 = __builtin_amdgcn_mfma_f32_16x16x32_bf16(kr[6], qf[qh][0], s3, 0, 0, 0);
    s3 = __builtin_amdgcn_mfma_f32_16x16x32_bf16(kr[7], qf[qh][1], s3, 0, 0, 0);
    // lane holds S[kv = 8*lg + {0..3,4..7,32..35,36..39}][q = l15]

    f32x4 mv = s0;
#pragma unroll
    for (int r = 0; r < 4; r++) mv[r] = fmaxf(fmaxf(mv[r], s1[r]), fmaxf(s2[r], s3[r]));
    float mx = fmaxf(fmaxf(mv[0], mv[1]), fmaxf(mv[2], mv[3]));
    mx = fmaxf(mx, __shfl_xor(mx, 16));
    mx = fmaxf(mx, __shfl_xor(mx, 32));
    const float mn = fmaxf(m[qh], mx);
    const float fr = exp2f((m[qh] - mn) * cexp);
    m[qh] = mn;
#pragma unroll
    for (int r = 0; r < 4; r++) {
      s0[r] = exp2f((s0[r] - mn) * cexp);
      s1[r] = exp2f((s1[r] - mn) * cexp);
      s2[r] = exp2f((s2[r] - mn) * cexp);
      s3[r] = exp2f((s3[r] - mn) * cexp);
    }
    f32x4 sv = (s0 + s1) + (s2 + s3);
    float ts = (sv[0] + sv[1]) + (sv[2] + sv[3]);
    ts += __shfl_xor(ts, 16);
    ts += __shfl_xor(ts, 32);
    sden[qh] = sden[qh] * fr + ts;

    bf16x8 pa0, pa1;
#pragma unroll
    for (int r = 0; r < 4; r++) {
      pa0[r]     = (short)f2bf(s0[r]);
      pa0[4 + r] = (short)f2bf(s1[r]);
      pa1[r]     = (short)f2bf(s2[r]);
      pa1[4 + r] = (short)f2bf(s3[r]);
    }

    float frq[4];
#pragma unroll
    for (int r = 0; r < 4; r++) frq[r] = __shfl(fr, 20 * lg + r, 64);
#pragma unroll
    for (int dg = 0; dg < 4; dg++) {
      oa[qh][dg][0] *= frq[0]; oa[qh][dg][1] *= frq[1];
      oa[qh][dg][2] *= frq[2]; oa[qh][dg][3] *= frq[3];
      oa[qh][dg] = __builtin_amdgcn_mfma_f32_16x16x32_bf16(pa0, vr[2 * dg],     oa[qh][dg], 0, 0, 0);
      oa[qh][dg] = __builtin_amdgcn_mfma_f32_16x16x32_bf16(pa1, vr[2 * dg + 1], oa[qh][dg], 0, 0, 0);
    }
  }
}

__global__ __launch_bounds__(256) void k_attn(const u16* __restrict__ QKV,
                                              const u16* __restrict__ Kp,
                                              const u16* __restrict__ Vp,
                                              u16* __restrict__ O) {
  const int Tn = 1024;
  const int bh = blockIdx.x, b = bh >> 4, h = bh & 15;
  const int q0 = blockIdx.y * 128;
  const int tid = threadIdx.x, wave = tid >> 6, lane = tid & 63;
  const int lg = lane >> 4, l15 = lane & 15;

  const u16* Qb = QKV + (size_t)(b * Tn + q0 + wave * 32 + l15) * 3072 + h * 64 + lg * 8;
  bf16x8 qf[2][2];
  qf[0][0] = *(const bf16x8*)Qb;
  qf[0][1] = *(const bf16x8*)(Qb + 32);
  qf[1][0] = *(const bf16x8*)(Qb + 16 * 3072);
  qf[1][1] = *(const bf16x8*)(Qb + 16 * 3072 + 32);

  const u16* KpB = Kp + (size_t)bh * 65536 + lane * 8;
  const u16* VpB = Vp + (size_t)bh * 65536 + lane * 8;

  const float cexp = 0.03125f * 1.44269504f;       // C^-0.5 * log2(e)

  float m[2] = {-1e30f, -1e30f}, sden[2] = {0.f, 0.f};
  const f32x4 zero = {0.f, 0.f, 0.f, 0.f};
  f32x4 oa[2][4];
#pragma unroll
  for (int qh = 0; qh < 2; qh++)
#pragma unroll
    for (int dg = 0; dg < 4; dg++) oa[qh][dg] = zero;

  bf16x8 ka[8], va[8], kb[8], vb[8];
  load8(ka, KpB);
  load8(va, VpB);

  for (int t = 0; t < 16; t += 2) {
    load8(kb, KpB + (t + 1) * 4096);
    load8(vb, VpB + (t + 1) * 4096);
    attn_tile32(ka, va, qf, oa, m, sden, lg, cexp);
    if (t + 2 < 16) {
      load8(ka, KpB + (t + 2) * 4096);
      load8(va, VpB + (t + 2) * 4096);
    }
    attn_tile32(kb, vb, qf, oa, m, sden, lg, cexp);
  }

#pragma unroll
  for (int qh = 0; qh < 2; qh++) {
    float sdq[4];
#pragma unroll
    for (int r = 0; r < 4; r++) sdq[r] = 1.f / __shfl(sden[qh], 20 * lg + r, 64);
    u16* Ob = O + (size_t)(b * Tn + q0 + wave * 32 + qh * 16) * 1024 + h * 64;
#pragma unroll
    for (int dg = 0; dg < 4; dg++)
#pragma unroll
      for (int r = 0; r < 4; r++)
        Ob[(size_t)(lg * 4 + r) * 1024 + dg * 16 + l15] = f2bf(oa[qh][dg][r] * sdq[r]);
  }
}

// ---------------------------------------------------------------------------
// Launch
// ---------------------------------------------------------------------------
extern "C" void kernel_launch(void* const* d_in, const int* in_sizes, int n_in,
                              void* d_out, int out_size, void* d_ws, size_t ws_size,
                              hipStream_t stream) {
  const float* x   = (const float*)d_in[0];
  const float* Wq1 = (const float*)d_in[1];
  const float* Wk1 = (const float*)d_in[2];
  const float* Wv1 = (const float*)d_in[3];
  const float* Wq2 = (const float*)d_in[4];
  const float* Wk2 = (const float*)d_in[5];
  const float* Wv2 = (const float*)d_in[6];
  const float* g1  = (const float*)d_in[7];
  const float* b1  = (const float*)d_in[8];
  const float* g2  = (const float*)d_in[9];
  const float* b2  = (const float*)d_in[10];
  const float* g3  = (const float*)d_in[11];
  const float* b3  = (const float*)d_in[12];
  const float* W1  = (const float*)d_in[13];
  const float* bf1 = (const float*)d_in[14];
  const float* W2  = (const float*)d_in[15];
  const float* bf2 = (const float*)d_in[16];

  char* ws = (char*)d_ws;
  // layout (bytes):
  u16* Wqkv1t = (u16*)(ws);                    //  6,291,456  [3072][1024]
  u16* Wqkv2t = (u16*)(ws + 6291456);          //  6,291,456
  u16* W1t    = (u16*)(ws + 12582912);         //  8,388,608  [4096][1024]
  u16* W2t    = (u16*)(ws + 20971520);         //  8,388,608  [1024][4096]
  u16* xn     = (u16*)(ws + 29360128);         //  8,388,608  [4096][1024]
  u16* QKV    = (u16*)(ws + 37748736);         // 25,165,824  [4096][3072]
  u16* Kp     = (u16*)(ws + 62914560);         //  8,388,608  frag-packed K
  u16* Vp     = (u16*)(ws + 71303168);         //  8,388,608  frag-packed V
  u16* O      = (u16*)(ws + 79691776);         //  8,388,608  attn out (bf16)
  u16* h1     = (u16*)(ws + 37748736);         // 33,554,432  aliases QKV+Kp (dead by MLP)
  // split-K partials (alive only during MLP2; alias dead regions):
  float* P0   = (float*)(ws);                  // 16,777,216  over Wqkv*/W1t (dead)
  float* P1   = (float*)(ws + 71303168);       // 16,777,216  over Vp+O (dead)
  float* xacc = (float*)d_out;                 // fp32 running residual in d_out
  // total ws = 88,080,384 bytes

  const dim3 blk(256);

  // weight packs
  k_pack_headw<<<dim3(16, 16), blk, 0, stream>>>(Wq1, Wqkv1t);
  k_pack_headw<<<dim3(16, 16), blk, 0, stream>>>(Wk1, Wqkv1t + 1024 * 1024);
  k_pack_headw<<<dim3(16, 16), blk, 0, stream>>>(Wv1, Wqkv1t + 2048 * 1024);
  k_pack_headw<<<dim3(16, 16), blk, 0, stream>>>(Wq2, Wqkv2t);
  k_pack_headw<<<dim3(16, 16), blk, 0, stream>>>(Wk2, Wqkv2t + 1024 * 1024);
  k_pack_headw<<<dim3(16, 16), blk, 0, stream>>>(Wv2, Wqkv2t + 2048 * 1024);
  k_transpose<<<dim3(64, 16), blk, 0, stream>>>(W1, W1t, 1024, 4096);
  k_transpose<<<dim3(16, 64), blk, 0, stream>>>(W2, W2t, 4096, 1024);

  // ---- layer 1 MSA ----
  k_ln<<<4096, blk, 0, stream>>>(x, nullptr, nullptr, xn, g1, b1);
  gemm_bt<0><<<dim3(24, 32), blk, 0, stream>>>(xn, Wqkv1t, QKV, nullptr, nullptr, 4096, 3072, 1024);
  k_packkv<<<dim3(16, 64), blk, 0, stream>>>(QKV, Kp, Vp);
  k_attn<<<dim3(64, 8), blk, 0, stream>>>(QKV, Kp, Vp, O);
  // x2 = x + O; xn = LN(x2)
  k_ln<<<4096, blk, 0, stream>>>(x, O, xacc, xn, g2, b2);

  // ---- layer 2 MSA ----
  gemm_bt<0><<<dim3(24, 32), blk, 0, stream>>>(xn, Wqkv2t, QKV, nullptr, nullptr, 4096, 3072, 1024);
  k_packkv<<<dim3(16, 64), blk, 0, stream>>>(QKV, Kp, Vp);
  k_attn<<<dim3(64, 8), blk, 0, stream>>>(QKV, Kp, Vp, O);
  // x3 = x2 + O (in place in d_out); xn = LN(x3)
  k_ln<<<4096, blk, 0, stream>>>(xacc, O, xacc, xn, g3, b3);

  // ---- MLP ----
  gemm_bt<1><<<dim3(32, 32), blk, 0, stream>>>(xn, W1t, h1, nullptr, bf1, 4096, 4096, 1024);
  gemm_bt<3><<<dim3(8, 32, 2), blk, 0, stream>>>(h1, W2t, P0, P1, nullptr, 4096, 1024, 4096);
  k_comb<<<4096, blk, 0, stream>>>(P0, P1, bf2, xacc);

  (void)in_sizes; (void)n_in; (void)out_size; (void)ws_size;
}

// Round 8
// 446.979 us; speedup vs baseline: 1.4191x; 1.0171x over previous
//
#include <hip/hip_runtime.h>

// ---------------------------------------------------------------------------
// Fused TransformerBlock: x += MSA(LN(x)) twice, then x += MLP(LN(x)).
// B=4 T=1024 C=1024 H=16 hd=64. fp32 residuals, bf16 GEMM/MFMA inputs.
// Round-8: + XCD-chunked block swizzle on all GEMMs (T1). Each XCD gets a
// contiguous row-major tile range -> A-panel stays hot in its private L2,
// cutting the 8.4x FETCH over-read seen on MLP1 (135MB vs 16MB ideal).
// ---------------------------------------------------------------------------

#define DEVI __device__ __forceinline__

typedef unsigned short u16;
typedef short bf16x8 __attribute__((ext_vector_type(8)));   // 8 bf16 = 4 VGPR
typedef float f32x4 __attribute__((ext_vector_type(4)));
typedef unsigned short u16x4 __attribute__((ext_vector_type(4)));

DEVI u16 f2bf(float f) {                 // RNE fp32 -> bf16
  union { float f; unsigned u; } v; v.f = f;
  unsigned r = v.u + 0x7FFFu + ((v.u >> 16) & 1u);
  return (u16)(r >> 16);
}
DEVI float bf2f(u16 u) {
  union { unsigned u; float f; } v; v.u = ((unsigned)u) << 16; return v.f;
}

DEVI void gload16(const void* g, void* l) {   // async global->LDS, 16B/lane
  __builtin_amdgcn_global_load_lds((const __attribute__((address_space(1))) void*)g,
                                   (__attribute__((address_space(3))) void*)l,
                                   16, 0, 0);
}

// ---------------------------------------------------------------------------
// Weight packs (fp32 -> bf16, transposed to Bt[N][K] layout for the GEMM)
// ---------------------------------------------------------------------------

// W [16][1024][64] fp32  ->  out rows [h*64+d][1024] bf16
__global__ __launch_bounds__(256) void k_pack_headw(const float* __restrict__ W,
                                                    u16* __restrict__ out) {
  const int k0 = blockIdx.x * 64;
  const int h  = blockIdx.y;
  __shared__ float t[64][65];
  const int tid = threadIdx.x;
#pragma unroll
  for (int p = 0; p < 16; p++) {
    int e = p * 256 + tid, kk = e >> 6, d = e & 63;
    t[kk][d] = W[h * 65536 + (k0 + kk) * 64 + d];
  }
  __syncthreads();
#pragma unroll
  for (int p = 0; p < 16; p++) {
    int e = p * 256 + tid, d = e >> 6, kk = e & 63;
    out[(size_t)(h * 64 + d) * 1024 + k0 + kk] = f2bf(t[kk][d]);
  }
}

// in [R][C] fp32 -> out [C][R] bf16
__global__ __launch_bounds__(256) void k_transpose(const float* __restrict__ in,
                                                   u16* __restrict__ out,
                                                   int R, int C) {
  const int c0 = blockIdx.x * 64, r0 = blockIdx.y * 64;
  __shared__ float t[64][65];
  const int tid = threadIdx.x;
#pragma unroll
  for (int p = 0; p < 16; p++) {
    int e = p * 256 + tid, rr = e >> 6, cc = e & 63;
    t[rr][cc] = in[(size_t)(r0 + rr) * C + c0 + cc];
  }
  __syncthreads();
#pragma unroll
  for (int p = 0; p < 16; p++) {
    int e = p * 256 + tid, cc = e >> 6, rr = e & 63;
    out[(size_t)(c0 + cc) * R + r0 + rr] = f2bf(t[rr][cc]);
  }
}

// ---------------------------------------------------------------------------
// LayerNorm (+ optional bf16 residual add): xv = xin (+ oin); writes fp32
// running residual (xsum) and bf16 normalized output (xn). One block per row.
// ---------------------------------------------------------------------------
__global__ __launch_bounds__(256) void k_ln(const float* __restrict__ xin,
                                            const u16* __restrict__ oin,
                                            float* __restrict__ xsum,
                                            u16* __restrict__ xn,
                                            const float* __restrict__ g,
                                            const float* __restrict__ b) {
  const int row = blockIdx.x;
  const size_t base = (size_t)row * 1024;
  const int tid = threadIdx.x;
  float4 xv = ((const float4*)(xin + base))[tid];
  if (oin) {
    u16x4 ov = *(const u16x4*)(oin + base + tid * 4);
    xv.x += bf2f(ov[0]); xv.y += bf2f(ov[1]);
    xv.z += bf2f(ov[2]); xv.w += bf2f(ov[3]);
  }
  if (xsum) ((float4*)(xsum + base))[tid] = xv;
  float s = xv.x + xv.y + xv.z + xv.w;
  float q = xv.x * xv.x + xv.y * xv.y + xv.z * xv.z + xv.w * xv.w;
#pragma unroll
  for (int m = 1; m < 64; m <<= 1) { s += __shfl_xor(s, m); q += __shfl_xor(q, m); }
  __shared__ float red[8];
  const int wave = tid >> 6, lane = tid & 63;
  if (lane == 0) { red[wave] = s; red[4 + wave] = q; }
  __syncthreads();
  s = red[0] + red[1] + red[2] + red[3];
  q = red[4] + red[5] + red[6] + red[7];
  const float mean = s * (1.f / 1024.f);
  const float var  = q * (1.f / 1024.f) - mean * mean;
  const float rstd = rsqrtf(var + 1e-5f);
  float4 gv = ((const float4*)g)[tid];
  float4 bv = ((const float4*)b)[tid];
  u16x4 o;
  o[0] = f2bf((xv.x - mean) * rstd * gv.x + bv.x);
  o[1] = f2bf((xv.y - mean) * rstd * gv.y + bv.y);
  o[2] = f2bf((xv.z - mean) * rstd * gv.z + bv.z);
  o[3] = f2bf((xv.w - mean) * rstd * gv.w + bv.w);
  *(u16x4*)(xn + base + tid * 4) = o;
}

// ---------------------------------------------------------------------------
// GEMM C[M,N] = A[M,K] * Bt[N,K]^T, bf16 in, fp32 accum.
// 128x128 tile, BK=32, 4 waves (2x2) x 64x64. 2-phase pipeline (LDS dbuf,
// STAGE(t+1) before COMPUTE(t), one barrier per half-iter). Source-side XOR
// swizzle (rule #21) keeps ds_read_b128 conflict-free with a linear
// global_load_lds dest. XCD-chunked block swizzle (T1): each XCD gets a
// contiguous row-major tile range for L2 panel reuse (nwg % 8 == 0 in all
// our launches).
// EPI 0: bf16 store. 1: +bias relu bf16. 3: split-K fp32 partial (z picks
// outp/outp2, K-range [z*K/2,(z+1)*K/2)).
// ---------------------------------------------------------------------------
template <int EPI>
__global__ __launch_bounds__(256, 4) void gemm_bt(const u16* __restrict__ A,
                                                  const u16* __restrict__ Bt,
                                                  void* __restrict__ outp,
                                                  void* __restrict__ outp2,
                                                  const float* __restrict__ bias,
                                                  int M, int N, int K) {
  __shared__ u16 As[2][128 * 32];
  __shared__ u16 Bs[2][128 * 32];
  const int tid = threadIdx.x;
  const int wave = tid >> 6, lane = tid & 63;
  const int lg = lane >> 4, l15 = lane & 15;
  const int wr = wave >> 1, wc = wave & 1;

  // T1: XCD-chunked bijective swizzle (nwg multiple of 8)
  const int nwg = gridDim.x * gridDim.y;
  int bid = blockIdx.y * gridDim.x + blockIdx.x;
  bid = (bid & 7) * (nwg >> 3) + (bid >> 3);
  const int by = bid / gridDim.x, bx = bid % gridDim.x;

  const int Ksz   = (EPI == 3) ? (K >> 1) : K;
  const int kbase = (EPI == 3) ? (int)blockIdx.z * Ksz : 0;

  const u16* Ab = A + (size_t)by * 128 * K;
  const u16* Bb = Bt + (size_t)bx * 128 * K;

  // staging chunks: c1 = tid -> (row r0, quad q); c2 = 256+tid -> (r0+64, q)
  const int r0 = tid >> 2, q = tid & 3, r1 = r0 + 64;
  const int c0s = (q ^ ((r0 >> 1) & 3)) * 8;   // swizzled source col (elems)
  const int c1s = (q ^ ((r1 >> 1) & 3)) * 8;
  // wave-uniform LDS bases (lane*16 added by HW)
  char* const a0[2] = {(char*)As[0] + wave * 1024, (char*)As[1] + wave * 1024};
  char* const a1[2] = {(char*)As[0] + 4096 + wave * 1024, (char*)As[1] + 4096 + wave * 1024};
  char* const b0[2] = {(char*)Bs[0] + wave * 1024, (char*)Bs[1] + wave * 1024};
  char* const b1[2] = {(char*)Bs[0] + 4096 + wave * 1024, (char*)Bs[1] + 4096 + wave * 1024};

#define STAGE(b, kk)                                       \
  gload16(Ab + (size_t)r0 * K + (kk) + c0s, a0[b]);        \
  gload16(Ab + (size_t)r1 * K + (kk) + c1s, a1[b]);        \
  gload16(Bb + (size_t)r0 * K + (kk) + c0s, b0[b]);        \
  gload16(Bb + (size_t)r1 * K + (kk) + c1s, b1[b]);

  // fragment byte offsets (loop-invariant; swizzled)
  int aoff[4], boff[4];
#pragma unroll
  for (int i = 0; i < 4; i++) {
    int Ra = wr * 64 + i * 16 + l15;
    aoff[i] = Ra * 64 + ((lg ^ ((Ra >> 1) & 3)) << 4);
    int Rb = wc * 64 + i * 16 + l15;
    boff[i] = Rb * 64 + ((lg ^ ((Rb >> 1) & 3)) << 4);
  }

  const f32x4 zero = {0.f, 0.f, 0.f, 0.f};
  f32x4 acc[4][4];
#pragma unroll
  for (int i = 0; i < 4; i++)
#pragma unroll
    for (int j = 0; j < 4; j++) acc[i][j] = zero;

#define COMPUTE(b)                                                             \
  {                                                                            \
    bf16x8 af[4], bfv[4];                                                      \
    _Pragma("unroll") for (int i = 0; i < 4; i++)                              \
        af[i] = *(const bf16x8*)((const char*)As[b] + aoff[i]);                \
    _Pragma("unroll") for (int j = 0; j < 4; j++)                              \
        bfv[j] = *(const bf16x8*)((const char*)Bs[b] + boff[j]);               \
    _Pragma("unroll") for (int i = 0; i < 4; i++)                              \
        _Pragma("unroll") for (int j = 0; j < 4; j++)                          \
            acc[i][j] = __builtin_amdgcn_mfma_f32_16x16x32_bf16(               \
                af[i], bfv[j], acc[i][j], 0, 0, 0);                            \
  }

  const int NT = Ksz >> 5;          // 32 (K=1024) or 64 (split K=4096): even
  STAGE(0, kbase);
  __syncthreads();                  // buf0 resident
  for (int t = 0; t < NT; t += 2) {
    STAGE(1, kbase + (t + 1) * 32);   // issue next tile, then compute current
    COMPUTE(0);
    __syncthreads();                  // buf1 resident; all reads of buf0 done
    if (t + 2 < NT) { STAGE(0, kbase + (t + 2) * 32); }
    COMPUTE(1);
    __syncthreads();
  }
#undef STAGE
#undef COMPUTE

  // C/D layout: col = lane&15, row = (lane>>4)*4 + reg  [m89/m91 verified]
  const int rbase = by * 128 + wr * 64 + lg * 4;
  const int cbase = bx * 128 + wc * 64 + l15;
  if constexpr (EPI == 0) {
    u16* out = (u16*)outp;
#pragma unroll
    for (int i = 0; i < 4; i++)
#pragma unroll
      for (int j = 0; j < 4; j++)
#pragma unroll
        for (int r = 0; r < 4; r++)
          out[(size_t)(rbase + i * 16 + r) * N + cbase + j * 16] = f2bf(acc[i][j][r]);
  } else if constexpr (EPI == 1) {
    u16* out = (u16*)outp;
#pragma unroll
    for (int j = 0; j < 4; j++) {
      const float bv = bias[cbase + j * 16];
#pragma unroll
      for (int i = 0; i < 4; i++)
#pragma unroll
        for (int r = 0; r < 4; r++)
          out[(size_t)(rbase + i * 16 + r) * N + cbase + j * 16] =
              f2bf(fmaxf(acc[i][j][r] + bv, 0.f));
    }
  } else {
    float* out = blockIdx.z ? (float*)outp2 : (float*)outp;
#pragma unroll
    for (int i = 0; i < 4; i++)
#pragma unroll
      for (int j = 0; j < 4; j++)
#pragma unroll
        for (int r = 0; r < 4; r++)
          out[(size_t)(rbase + i * 16 + r) * N + cbase + j * 16] = acc[i][j][r];
  }
}

// combine split-K partials: xacc += P0 + P1 + bias  (one row per block)
__global__ __launch_bounds__(256) void k_comb(const float* __restrict__ P0,
                                              const float* __restrict__ P1,
                                              const float* __restrict__ bias,
                                              float* __restrict__ xacc) {
  const size_t i = (size_t)blockIdx.x * 1024 + threadIdx.x * 4;
  float4 a = *(const float4*)(P0 + i);
  float4 b = *(const float4*)(P1 + i);
  float4 x = *(const float4*)(xacc + i);
  float4 bv = *(const float4*)(bias + threadIdx.x * 4);
  x.x += a.x + b.x + bv.x;
  x.y += a.y + b.y + bv.y;
  x.z += a.z + b.z + bv.z;
  x.w += a.w + b.w + bv.w;
  *(float4*)(xacc + i) = x;
}

// ---------------------------------------------------------------------------
// K/V fragment pack. Block = (kv-tile t, bh). Stages the 64x64 bf16 tile in
// LDS (coalesced global reads), emits MFMA-fragment-ordered chunks so k_attn
// loads are lane-linear 1KB streams.
// ---------------------------------------------------------------------------
__global__ __launch_bounds__(256) void k_packkv(const u16* __restrict__ QKV,
                                                u16* __restrict__ Kp,
                                                u16* __restrict__ Vp) {
  const int t  = blockIdx.x;               // kv tile 0..15
  const int bh = blockIdx.y, b = bh >> 4, h = bh & 15;
  const int tid = threadIdx.x;
  __shared__ u16 vt[64][80];               // 80: 16B-aligned rows, bank-spread

  const u16* Ksrc = QKV + (size_t)(b * 1024 + t * 64) * 3072 + 1024 + h * 64;
  const u16* Vsrc = QKV + (size_t)(b * 1024 + t * 64) * 3072 + 2048 + h * 64;
  u16* KpT = Kp + (size_t)(bh * 16 + t) * 4096;
  u16* VpT = Vp + (size_t)(bh * 16 + t) * 4096;

  // ---- stage K tile, emit Kp ----
#pragma unroll
  for (int p = 0; p < 2; p++) {
    int e = p * 256 + tid, rr = e >> 3, dd = (e & 7) * 8;
    *(bf16x8*)&vt[rr][dd] = *(const bf16x8*)(Ksrc + (size_t)rr * 3072 + dd);
  }
  __syncthreads();
#pragma unroll
  for (int p = 0; p < 2; p++) {
    int c = p * 256 + tid;
    int i = c >> 6, lane = c & 63, lgg = lane >> 4, ll = lane & 15;
    int j = i >> 1;
    int row = 8 * (ll >> 2) + (ll & 3) + (j & 1) * 4 + (j >> 1) * 32;
    int col = (i & 1) * 32 + lgg * 8;
    *(bf16x8*)&KpT[(size_t)c * 8] = *(const bf16x8*)&vt[row][col];
  }
  __syncthreads();
  // ---- stage V tile, emit Vp (transposed) ----
#pragma unroll
  for (int p = 0; p < 2; p++) {
    int e = p * 256 + tid, rr = e >> 3, dd = (e & 7) * 8;
    *(bf16x8*)&vt[rr][dd] = *(const bf16x8*)(Vsrc + (size_t)rr * 3072 + dd);
  }
  __syncthreads();
#pragma unroll
  for (int p = 0; p < 2; p++) {
    int c = p * 256 + tid;
    int i = c >> 6, lane = c & 63, lgg = lane >> 4, ll = lane & 15;
    int dg = (i >> 1) & 3, kh = i & 1;
    bf16x8 o;
#pragma unroll
    for (int jj = 0; jj < 8; jj++)
      o[jj] = (short)vt[kh * 32 + lgg * 8 + jj][dg * 16 + ll];
    *(bf16x8*)&VpT[(size_t)c * 8] = o;
  }
}

// ---------------------------------------------------------------------------
// Flash attention fwd. Swapped QK^T, fragment-packed K/V (coalesced streams),
// 32 q-rows per wave (two 16-row halves share K/V regs), KVBLK=64, reg dbuf.
// Block = (b,h) x 128 q-rows, 4 waves. No LDS. O written bf16.
// ---------------------------------------------------------------------------
DEVI void load8(bf16x8 (&r)[8], const u16* p) {   // p includes +lane*8
#pragma unroll
  for (int i = 0; i < 8; i++) r[i] = *(const bf16x8*)(p + i * 512);
}

DEVI void attn_tile32(const bf16x8 (&kr)[8], const bf16x8 (&vr)[8],
                      const bf16x8 (&qf)[2][2], f32x4 (&oa)[2][4],
                      float (&m)[2], float (&sden)[2], int lg, float cexp) {
  const f32x4 zero = {0.f, 0.f, 0.f, 0.f};
#pragma unroll
  for (int qh = 0; qh < 2; qh++) {
    f32x4 s0 = zero, s1 = zero, s2 = zero, s3 = zero;
    s0 = __builtin_amdgcn_mfma_f32_16x16x32_bf16(kr[0], qf[qh][0], s0, 0, 0, 0);
    s0 = __builtin_amdgcn_mfma_f32_16x16x32_bf16(kr[1], qf[qh][1], s0, 0, 0, 0);
    s1 = __builtin_amdgcn_mfma_f32_16x16x32_bf16(kr[2], qf[qh][0], s1, 0, 0, 0);
    s1 = __builtin_amdgcn_mfma_f32_16x16x32_bf16(kr[3], qf[qh][1], s1, 0, 0, 0);
    s2 = __builtin_amdgcn_mfma_f32_16x16x32_bf16(kr[4], qf[qh][0], s2, 0, 0, 0);
    s2 = __builtin_amdgcn_mfma_f32_16x16x32_bf16(kr[5], qf[qh][1], s2, 0, 0, 0);
    s3 = __builtin_amdgcn_mfma_f32_16x16x32_bf16(kr[6], qf[qh][0], s3, 0, 0, 0);
    s3 = __builtin_amdgcn_mfma_f32_16x16x32_bf16(kr[7], qf[qh][1], s3, 0, 0, 0);
    // lane holds S[kv = 8*lg + {0..3,4..7,32..35,36..39}][q = l15]

    f32x4 mv = s0;
#pragma unroll
    for (int r = 0; r < 4; r++) mv[r] = fmaxf(fmaxf(mv[r], s1[r]), fmaxf(s2[r], s3[r]));
    float mx = fmaxf(fmaxf(mv[0], mv[1]), fmaxf(mv[2], mv[3]));
    mx = fmaxf(mx, __shfl_xor(mx, 16));
    mx = fmaxf(mx, __shfl_xor(mx, 32));
    const float mn = fmaxf(m[qh], mx);
    const float fr = exp2f((m[qh] - mn) * cexp);
    m[qh] = mn;
#pragma unroll
    for (int r = 0; r < 4; r++) {
      s0[r] = exp2f((s0[r] - mn) * cexp);
      s1[r] = exp2f((s1[r] - mn) * cexp);
      s2[r] = exp2f((s2[r] - mn) * cexp);
      s3[r] = exp2f((s3[r] - mn) * cexp);
    }
    f32x4 sv = (s0 + s1) + (s2 + s3);
    float ts = (sv[0] + sv[1]) + (sv[2] + sv[3]);
    ts += __shfl_xor(ts, 16);
    ts += __shfl_xor(ts, 32);
    sden[qh] = sden[qh] * fr + ts;

    bf16x8 pa0, pa1;
#pragma unroll
    for (int r = 0; r < 4; r++) {
      pa0[r]     = (short)f2bf(s0[r]);
      pa0[4 + r] = (short)f2bf(s1[r]);
      pa1[r]     = (short)f2bf(s2[r]);
      pa1[4 + r] = (short)f2bf(s3[r]);
    }

    float frq[4];
#pragma unroll
    for (int r = 0; r < 4; r++) frq[r] = __shfl(fr, 20 * lg + r, 64);
#pragma unroll
    for (int dg = 0; dg < 4; dg++) {
      oa[qh][dg][0] *= frq[0]; oa[qh][dg][1] *= frq[1];
      oa[qh][dg][2] *= frq[2]; oa[qh][dg][3] *= frq[3];
      oa[qh][dg] = __builtin_amdgcn_mfma_f32_16x16x32_bf16(pa0, vr[2 * dg],     oa[qh][dg], 0, 0, 0);
      oa[qh][dg] = __builtin_amdgcn_mfma_f32_16x16x32_bf16(pa1, vr[2 * dg + 1], oa[qh][dg], 0, 0, 0);
    }
  }
}

__global__ __launch_bounds__(256) void k_attn(const u16* __restrict__ QKV,
                                              const u16* __restrict__ Kp,
                                              const u16* __restrict__ Vp,
                                              u16* __restrict__ O) {
  const int Tn = 1024;
  const int bh = blockIdx.x, b = bh >> 4, h = bh & 15;
  const int q0 = blockIdx.y * 128;
  const int tid = threadIdx.x, wave = tid >> 6, lane = tid & 63;
  const int lg = lane >> 4, l15 = lane & 15;

  const u16* Qb = QKV + (size_t)(b * Tn + q0 + wave * 32 + l15) * 3072 + h * 64 + lg * 8;
  bf16x8 qf[2][2];
  qf[0][0] = *(const bf16x8*)Qb;
  qf[0][1] = *(const bf16x8*)(Qb + 32);
  qf[1][0] = *(const bf16x8*)(Qb + 16 * 3072);
  qf[1][1] = *(const bf16x8*)(Qb + 16 * 3072 + 32);

  const u16* KpB = Kp + (size_t)bh * 65536 + lane * 8;
  const u16* VpB = Vp + (size_t)bh * 65536 + lane * 8;

  const float cexp = 0.03125f * 1.44269504f;       // C^-0.5 * log2(e)

  float m[2] = {-1e30f, -1e30f}, sden[2] = {0.f, 0.f};
  const f32x4 zero = {0.f, 0.f, 0.f, 0.f};
  f32x4 oa[2][4];
#pragma unroll
  for (int qh = 0; qh < 2; qh++)
#pragma unroll
    for (int dg = 0; dg < 4; dg++) oa[qh][dg] = zero;

  bf16x8 ka[8], va[8], kb[8], vb[8];
  load8(ka, KpB);
  load8(va, VpB);

  for (int t = 0; t < 16; t += 2) {
    load8(kb, KpB + (t + 1) * 4096);
    load8(vb, VpB + (t + 1) * 4096);
    attn_tile32(ka, va, qf, oa, m, sden, lg, cexp);
    if (t + 2 < 16) {
      load8(ka, KpB + (t + 2) * 4096);
      load8(va, VpB + (t + 2) * 4096);
    }
    attn_tile32(kb, vb, qf, oa, m, sden, lg, cexp);
  }

#pragma unroll
  for (int qh = 0; qh < 2; qh++) {
    float sdq[4];
#pragma unroll
    for (int r = 0; r < 4; r++) sdq[r] = 1.f / __shfl(sden[qh], 20 * lg + r, 64);
    u16* Ob = O + (size_t)(b * Tn + q0 + wave * 32 + qh * 16) * 1024 + h * 64;
#pragma unroll
    for (int dg = 0; dg < 4; dg++)
#pragma unroll
      for (int r = 0; r < 4; r++)
        Ob[(size_t)(lg * 4 + r) * 1024 + dg * 16 + l15] = f2bf(oa[qh][dg][r] * sdq[r]);
  }
}

// ---------------------------------------------------------------------------
// Launch
// ---------------------------------------------------------------------------
extern "C" void kernel_launch(void* const* d_in, const int* in_sizes, int n_in,
                              void* d_out, int out_size, void* d_ws, size_t ws_size,
                              hipStream_t stream) {
  const float* x   = (const float*)d_in[0];
  const float* Wq1 = (const float*)d_in[1];
  const float* Wk1 = (const float*)d_in[2];
  const float* Wv1 = (const float*)d_in[3];
  const float* Wq2 = (const float*)d_in[4];
  const float* Wk2 = (const float*)d_in[5];
  const float* Wv2 = (const float*)d_in[6];
  const float* g1  = (const float*)d_in[7];
  const float* b1  = (const float*)d_in[8];
  const float* g2  = (const float*)d_in[9];
  const float* b2  = (const float*)d_in[10];
  const float* g3  = (const float*)d_in[11];
  const float* b3  = (const float*)d_in[12];
  const float* W1  = (const float*)d_in[13];
  const float* bf1 = (const float*)d_in[14];
  const float* W2  = (const float*)d_in[15];
  const float* bf2 = (const float*)d_in[16];

  char* ws = (char*)d_ws;
  // layout (bytes):
  u16* Wqkv1t = (u16*)(ws);                    //  6,291,456  [3072][1024]
  u16* Wqkv2t = (u16*)(ws + 6291456);          //  6,291,456
  u16* W1t    = (u16*)(ws + 12582912);         //  8,388,608  [4096][1024]
  u16* W2t    = (u16*)(ws + 20971520);         //  8,388,608  [1024][4096]
  u16* xn     = (u16*)(ws + 29360128);         //  8,388,608  [4096][1024]
  u16* QKV    = (u16*)(ws + 37748736);         // 25,165,824  [4096][3072]
  u16* Kp     = (u16*)(ws + 62914560);         //  8,388,608  frag-packed K
  u16* Vp     = (u16*)(ws + 71303168);         //  8,388,608  frag-packed V
  u16* O      = (u16*)(ws + 79691776);         //  8,388,608  attn out (bf16)
  u16* h1     = (u16*)(ws + 37748736);         // 33,554,432  aliases QKV+Kp (dead by MLP)
  // split-K partials (alive only during MLP2; alias dead regions):
  float* P0   = (float*)(ws);                  // 16,777,216  over Wqkv*/W1t (dead)
  float* P1   = (float*)(ws + 71303168);       // 16,777,216  over Vp+O (dead)
  float* xacc = (float*)d_out;                 // fp32 running residual in d_out
  // total ws = 88,080,384 bytes

  const dim3 blk(256);

  // weight packs
  k_pack_headw<<<dim3(16, 16), blk, 0, stream>>>(Wq1, Wqkv1t);
  k_pack_headw<<<dim3(16, 16), blk, 0, stream>>>(Wk1, Wqkv1t + 1024 * 1024);
  k_pack_headw<<<dim3(16, 16), blk, 0, stream>>>(Wv1, Wqkv1t + 2048 * 1024);
  k_pack_headw<<<dim3(16, 16), blk, 0, stream>>>(Wq2, Wqkv2t);
  k_pack_headw<<<dim3(16, 16), blk, 0, stream>>>(Wk2, Wqkv2t + 1024 * 1024);
  k_pack_headw<<<dim3(16, 16), blk, 0, stream>>>(Wv2, Wqkv2t + 2048 * 1024);
  k_transpose<<<dim3(64, 16), blk, 0, stream>>>(W1, W1t, 1024, 4096);
  k_transpose<<<dim3(16, 64), blk, 0, stream>>>(W2, W2t, 4096, 1024);

  // ---- layer 1 MSA ----
  k_ln<<<4096, blk, 0, stream>>>(x, nullptr, nullptr, xn, g1, b1);
  gemm_bt<0><<<dim3(24, 32), blk, 0, stream>>>(xn, Wqkv1t, QKV, nullptr, nullptr, 4096, 3072, 1024);
  k_packkv<<<dim3(16, 64), blk, 0, stream>>>(QKV, Kp, Vp);
  k_attn<<<dim3(64, 8), blk, 0, stream>>>(QKV, Kp, Vp, O);
  // x2 = x + O; xn = LN(x2)
  k_ln<<<4096, blk, 0, stream>>>(x, O, xacc, xn, g2, b2);

  // ---- layer 2 MSA ----
  gemm_bt<0><<<dim3(24, 32), blk, 0, stream>>>(xn, Wqkv2t, QKV, nullptr, nullptr, 4096, 3072, 1024);
  k_packkv<<<dim3(16, 64), blk, 0, stream>>>(QKV, Kp, Vp);
  k_attn<<<dim3(64, 8), blk, 0, stream>>>(QKV, Kp, Vp, O);
  // x3 = x2 + O (in place in d_out); xn = LN(x3)
  k_ln<<<4096, blk, 0, stream>>>(xacc, O, xacc, xn, g3, b3);

  // ---- MLP ----
  gemm_bt<1><<<dim3(32, 32), blk, 0, stream>>>(xn, W1t, h1, nullptr, bf1, 4096, 4096, 1024);
  gemm_bt<3><<<dim3(8, 32, 2), blk, 0, stream>>>(h1, W2t, P0, P1, nullptr, 4096, 1024, 4096);
  k_comb<<<4096, blk, 0, stream>>>(P0, P1, bf2, xacc);

  (void)in_sizes; (void)n_in; (void)out_size; (void)ws_size;
}